// Round 5
// baseline (533.045 us; speedup 1.0000x reference)
//
#include <hip/hip_runtime.h>
#include <math.h>

typedef unsigned long long u64;

// ---------------------------------------------------------------------------
// Kernel 1: KNN, bit-exact vs the np/fp32 reference:
//   sq = ((x*x+y*y)+z*z); dot = ((xi*xj+yi*yj)+zi*zj); d = (sqi+sqj)-2*dot
//   (fp32, no FMA contraction), stable top_k(101) (ties -> lower index),
//   drop rank 0.
// Keys: monotone uint32 of d (<<10) | local index  -> one u64 compare gives
// the full lexicographic (d, j) order. Per lane: 16 candidates, bitonic-
// sorted once; extraction = u64 min-butterfly + winner shift-pop.
// One wave per row, 4 rows per 256-thread block.
// ---------------------------------------------------------------------------
__global__ __launch_bounds__(256) void knn_kernel(const float* __restrict__ verts,
                                                  int* __restrict__ idx_out,
                                                  float* __restrict__ nd_out)
{
    __shared__ float vx[1024], vy[1024], vz[1024], sq[1024];
    const int tid = threadIdx.x;
    const int row0 = blockIdx.x * 4;
    const int b = row0 >> 10;            // block never crosses a batch
    const float* vb = verts + b * 3072;

    for (int t = tid; t < 3072; t += 256) {
        float v = vb[t];
        int n = t / 3, c = t - n * 3;
        if (c == 0) vx[n] = v; else if (c == 1) vy[n] = v; else vz[n] = v;
    }
    __syncthreads();
    for (int n = tid; n < 1024; n += 256) {
        float x = vx[n], y = vy[n], z = vz[n];
        sq[n] = __fadd_rn(__fadd_rn(__fmul_rn(x, x), __fmul_rn(y, y)),
                          __fmul_rn(z, z));
    }
    __syncthreads();

    const int w = tid >> 6, lane = tid & 63;
    const int row = row0 + w;
    const int n_i = row & 1023;
    const float xi = vx[n_i], yi = vy[n_i], zi = vz[n_i];
    const float sqi = sq[n_i];

    u64 K[16];
#pragma unroll
    for (int t = 0; t < 16; ++t) {
        int j = t * 64 + lane;
        float dot = __fadd_rn(__fadd_rn(__fmul_rn(xi, vx[j]),
                                        __fmul_rn(yi, vy[j])),
                              __fmul_rn(zi, vz[j]));
        float d = __fsub_rn(__fadd_rn(sqi, sq[j]), __fmul_rn(2.0f, dot));
        d = __fadd_rn(d, 0.0f);          // canonicalize -0.0 -> +0.0
        unsigned u = __float_as_uint(d);
        unsigned m = (u & 0x80000000u) ? ~u : (u | 0x80000000u);
        K[t] = ((u64)m << 10) | (unsigned)j;
    }

    // in-register bitonic sort, ascending (keys unique -> stable by idx)
#pragma unroll
    for (int k2 = 2; k2 <= 16; k2 <<= 1)
#pragma unroll
        for (int jj = k2 >> 1; jj > 0; jj >>= 1)
#pragma unroll
            for (int i = 0; i < 16; ++i) {
                int l = i ^ jj;
                if (l > i) {
                    bool up = ((i & k2) == 0);
                    bool sw = up ? (K[i] > K[l]) : (K[i] < K[l]);
                    u64 a = K[i], c = K[l];
                    K[i] = sw ? c : a;
                    K[l] = sw ? a : c;
                }
            }

    unsigned s0 = 0, s1 = 0;
    for (int it = 0; it < 101; ++it) {
        u64 bk = K[0];
#pragma unroll
        for (int off = 1; off < 64; off <<= 1) {
            u64 ok = __shfl_xor(bk, off);
            if (ok < bk) bk = ok;
        }
        unsigned j = (unsigned)bk & 1023u;
        if ((int)(j & 63u) == lane) {    // winner pops its head
#pragma unroll
            for (int t = 0; t < 15; ++t) K[t] = K[t + 1];
            K[15] = ~0ULL;
        }
        if (it == lane)      s0 = j;
        if (it == 64 + lane) s1 = j;
    }

    // parallel epilogue: lane L writes ranks L and 64+L (rank 0 dropped)
    const int rowbase = row & ~1023;
#pragma unroll
    for (int e = 0; e < 2; ++e) {
        int itv = lane + 64 * e;
        unsigned j = e ? s1 : s0;
        if (itv >= 1 && itv <= 100) {
            int slot = itv - 1;
            idx_out[row * 100 + slot] = rowbase + (int)j;
            float dx = vx[j] - xi, dy = vy[j] - yi, dz = vz[j] - zi;
            float nrm = sqrtf(__fadd_rn(__fadd_rn(__fmul_rn(dx, dx),
                                                  __fmul_rn(dy, dy)),
                                        __fmul_rn(dz, dz)));
            float inv = 1.0f / fmaxf(nrm, 1e-12f);
            float* o = nd_out + (row * 100 + slot) * 3;
            o[0] = dx * inv; o[1] = dy * inv; o[2] = dz * inv;
        }
    }
}

// ---------------------------------------------------------------------------
// Kernel 2: fused surface conv (3 scales) + per-block fp64 BN partial sums.
// 4 rows per 128-thread block; thread d = channel d.
// Partials: p[(2c)*1024 + blk] = sum, p[(2c+1)*1024 + blk] = sumsq.
// ---------------------------------------------------------------------------
__global__ __launch_bounds__(128) void surf3_kernel(const float* __restrict__ nd,
    const float* __restrict__ dl, const float* __restrict__ dm, const float* __restrict__ dg,
    float* __restrict__ raw_l, float* __restrict__ raw_m, float* __restrict__ raw_g,
    double* __restrict__ pl, double* __restrict__ pm, double* __restrict__ pg)
{
    __shared__ float nds[4 * 300];
    const int d = threadIdx.x;
    const int row0 = blockIdx.x * 4;

    float lx = dl[d], ly = dl[128 + d], lz = dl[256 + d];
    float li = 1.0f / fmaxf(sqrtf((lx * lx + ly * ly) + lz * lz), 1e-12f);
    lx *= li; ly *= li; lz *= li;
    float mx = dm[d], my = dm[128 + d], mz = dm[256 + d];
    float mi = 1.0f / fmaxf(sqrtf((mx * mx + my * my) + mz * mz), 1e-12f);
    mx *= mi; my *= mi; mz *= mi;
    float gx = dg[d], gy = dg[128 + d], gz = dg[256 + d];
    float gi = 1.0f / fmaxf(sqrtf((gx * gx + gy * gy) + gz * gz), 1e-12f);
    gx *= gi; gy *= gi; gz *= gi;

    for (int r = 0; r < 4; ++r)
        for (int t = d; t < 300; t += 128)
            nds[r * 300 + t] = nd[(row0 + r) * 300 + t];
    __syncthreads();

    double sl = 0, ql = 0, sm = 0, qm = 0, sg = 0, qg = 0;
    for (int r = 0; r < 4; ++r) {
        const float* ns = nds + r * 300;
        float ml = -1e30f, mm = -1e30f, mg = -1e30f;
        for (int k = 0; k < 100; ++k) {
            float x = ns[3 * k], y = ns[3 * k + 1], z = ns[3 * k + 2];
            mg = fmaxf(mg, (x * gx + y * gy) + z * gz);
            if (k < 20) mm = fmaxf(mm, (x * mx + y * my) + z * mz);
            if (k < 5)  ml = fmaxf(ml, (x * lx + y * ly) + z * lz);
        }
        float vl = fmaxf(ml, 0.0f), vm = fmaxf(mm, 0.0f), vg = fmaxf(mg, 0.0f);
        raw_l[(row0 + r) * 128 + d] = vl;
        raw_m[(row0 + r) * 128 + d] = vm;
        raw_g[(row0 + r) * 128 + d] = vg;
        sl += vl; ql += (double)vl * vl;
        sm += vm; qm += (double)vm * vm;
        sg += vg; qg += (double)vg * vg;
    }
    const int blk = blockIdx.x;
    pl[(2 * d) * 1024 + blk] = sl; pl[(2 * d + 1) * 1024 + blk] = ql;
    pm[(2 * d) * 1024 + blk] = sm; pm[(2 * d + 1) * 1024 + blk] = qm;
    pg[(2 * d) * 1024 + blk] = sg; pg[(2 * d + 1) * 1024 + blk] = qg;
}

// ---------------------------------------------------------------------------
// Kernel 3: finalize BN: reduce fp64 partials -> st[c]=a, st[128+c]=b2 with
// bn_relu(x) = relu(a*x+b2). One wave per (tensor, channel).
// ---------------------------------------------------------------------------
__global__ __launch_bounds__(64) void fin_kernel(
    const double* p0, const float* g0, const float* e0, float* st0,
    const double* p1, const float* g1, const float* e1, float* st1,
    const double* p2, const float* g2, const float* e2, float* st2,
    int NB)
{
    const int t = blockIdx.x >> 7, c = blockIdx.x & 127;
    const double* p = (t == 0) ? p0 : (t == 1) ? p1 : p2;
    const float* g = (t == 0) ? g0 : (t == 1) ? g1 : g2;
    const float* e = (t == 0) ? e0 : (t == 1) ? e1 : e2;
    float* st = (t == 0) ? st0 : (t == 1) ? st1 : st2;
    const int lane = threadIdx.x;
    double s = 0.0, q = 0.0;
    for (int i = lane; i < NB; i += 64) {
        s += p[(2 * c) * NB + i];
        q += p[(2 * c + 1) * NB + i];
    }
#pragma unroll
    for (int off = 32; off; off >>= 1) {
        s += __shfl_down(s, off);
        q += __shfl_down(q, off);
    }
    if (lane == 0) {
        double m = s * (1.0 / 4096.0);
        double var = q * (1.0 / 4096.0) - m * m;
        double a = (double)g[c] / sqrt(var + 1e-5);
        st[c] = (float)a;
        st[128 + c] = (float)((double)e[c] - m * a);
    }
}

// ---------------------------------------------------------------------------
// Kernel 4: dual-job GEMM (CIN=128): out[r][o] = bias[o] + sum_c bn_relu(A) W
// Job picked by blockIdx.y. Block 256 = 256 cols x 16 rows.
// ---------------------------------------------------------------------------
__global__ __launch_bounds__(256) void gemm2_kernel(
    const float* __restrict__ Aa, const float* __restrict__ sta,
    const float* __restrict__ Wa, const float* __restrict__ ba, float* __restrict__ outa,
    const float* __restrict__ Ab, const float* __restrict__ stb,
    const float* __restrict__ Wb, const float* __restrict__ bb, float* __restrict__ outb)
{
    const int job = blockIdx.y;
    const float* A = job ? Ab : Aa;  const float* st = job ? stb : sta;
    const float* W = job ? Wb : Wa;  const float* bias = job ? bb : ba;
    float* out = job ? outb : outa;

    __shared__ float As[16 * 128];
    const int o = threadIdx.x;
    const int r0 = blockIdx.x * 16;

    for (int t = o; t < 16 * 128; t += 256) {
        int r = t >> 7, c = t & 127;
        As[t] = fmaxf(fmaf(st[c], A[(r0 + r) * 128 + c], st[128 + c]), 0.0f);
    }
    __syncthreads();

    float acc[16];
    const float bz = bias[o];
#pragma unroll
    for (int r = 0; r < 16; ++r) acc[r] = bz;

    for (int c = 0; c < 128; c += 4) {
        float w0 = W[(c + 0) * 256 + o];
        float w1 = W[(c + 1) * 256 + o];
        float w2 = W[(c + 2) * 256 + o];
        float w3 = W[(c + 3) * 256 + o];
#pragma unroll
        for (int r = 0; r < 16; ++r) {
            const float4 av = *(const float4*)&As[r * 128 + c];
            acc[r] += av.x * w0 + av.y * w1 + av.z * w2 + av.w * w3;
        }
    }
#pragma unroll
    for (int r = 0; r < 16; ++r)
        out[(r0 + r) * 256 + o] = acc[r];
}

// ---------------------------------------------------------------------------
// Kernel 5: conv-layer apply + fp64 BN partials. 8 rows per 128-thread block;
// up to 2 jobs via blockIdx.y.
// out[r][d] = fo[r][d] + max_k relu(nd_k . ndir_d) * fo[idx_k][128+d]
// ---------------------------------------------------------------------------
__global__ __launch_bounds__(128) void layer_kernel(
    const float* __restrict__ nd, const int* __restrict__ idxbuf,
    const float* dir0, const float* fo0, float* out0, int K0, double* p0,
    const float* dir1, const float* fo1, float* out1, int K1, double* p1)
{
    const int job = blockIdx.y;
    const float* dirs = job ? dir1 : dir0;
    const float* fo = job ? fo1 : fo0;
    float* out = job ? out1 : out0;
    const int K = job ? K1 : K0;
    double* p = job ? p1 : p0;

    __shared__ float nds[8 * 300];
    __shared__ int idxs[8 * 100];
    const int d = threadIdx.x;
    const int row0 = blockIdx.x * 8;

    float dx = dirs[d], dy = dirs[128 + d], dz = dirs[256 + d];
    float di = 1.0f / fmaxf(sqrtf((dx * dx + dy * dy) + dz * dz), 1e-12f);
    dx *= di; dy *= di; dz *= di;

    for (int r = 0; r < 8; ++r) {
        for (int t = d; t < 300; t += 128)
            nds[r * 300 + t] = nd[(row0 + r) * 300 + t];
        if (d < 100) idxs[r * 100 + d] = idxbuf[(row0 + r) * 100 + d];
    }
    __syncthreads();

    double s = 0.0, q = 0.0;
    for (int r = 0; r < 8; ++r) {
        const float* ns = nds + r * 300;
        const int* ix = idxs + r * 100;
        float acc = -1e30f;
        for (int k = 0; k < K; ++k) {
            float th = fmaxf((ns[3 * k] * dx + ns[3 * k + 1] * dy) + ns[3 * k + 2] * dz, 0.0f);
            float fs = fo[ix[k] * 256 + 128 + d];   // global row index
            acc = fmaxf(acc, th * fs);
        }
        float v = fo[(row0 + r) * 256 + d] + acc;
        out[(row0 + r) * 128 + d] = v;
        s += v; q += (double)v * v;
    }
    p[(2 * d) * 512 + blockIdx.x] = s;
    p[(2 * d + 1) * 512 + blockIdx.x] = q;
}

// ---------------------------------------------------------------------------
// Kernel 6: final GEMM (CIN=384 from 3 bn_relu'd segments) + relu, fp32 out.
// ---------------------------------------------------------------------------
__global__ __launch_bounds__(256) void gemmf_kernel(
    const float* __restrict__ A0, const float* __restrict__ A1, const float* __restrict__ A2,
    const float* __restrict__ st0, const float* __restrict__ st1, const float* __restrict__ st2,
    const float* __restrict__ W, const float* __restrict__ bias, float* __restrict__ out)
{
    __shared__ float As[16 * 384];
    const int o = threadIdx.x;
    const int r0 = blockIdx.x * 16;

    for (int t = o; t < 16 * 384; t += 256) {
        int r = t / 384, c = t - r * 384;
        int seg = c >> 7, cc = c & 127;
        const float* A = (seg == 0) ? A0 : (seg == 1) ? A1 : A2;
        const float* st = (seg == 0) ? st0 : (seg == 1) ? st1 : st2;
        As[t] = fmaxf(fmaf(st[cc], A[(r0 + r) * 128 + cc], st[128 + cc]), 0.0f);
    }
    __syncthreads();

    float acc[16];
    const float bz = bias[o];
#pragma unroll
    for (int r = 0; r < 16; ++r) acc[r] = bz;

    for (int c = 0; c < 384; c += 4) {
        float w0 = W[(c + 0) * 256 + o];
        float w1 = W[(c + 1) * 256 + o];
        float w2 = W[(c + 2) * 256 + o];
        float w3 = W[(c + 3) * 256 + o];
#pragma unroll
        for (int r = 0; r < 16; ++r) {
            const float4 av = *(const float4*)&As[r * 384 + c];
            acc[r] += av.x * w0 + av.y * w1 + av.z * w2 + av.w * w3;
        }
    }
#pragma unroll
    for (int r = 0; r < 16; ++r)
        out[(r0 + r) * 256 + o] = fmaxf(acc[r], 0.0f);
}

// ---------------------------------------------------------------------------
extern "C" void kernel_launch(void* const* d_in, const int* in_sizes, int n_in,
                              void* d_out, int out_size, void* d_ws, size_t ws_size,
                              hipStream_t stream)
{
    (void)in_sizes; (void)n_in; (void)out_size; (void)ws_size;

    const float* verts   = (const float*)d_in[0];
    const float* dirs_l  = (const float*)d_in[1];
    const float* dirs_m0 = (const float*)d_in[2];
    const float* W_m1    = (const float*)d_in[3];
    const float* b_m1    = (const float*)d_in[4];
    const float* dirs_m1 = (const float*)d_in[5];
    const float* dirs_g0 = (const float*)d_in[6];
    const float* W_g1    = (const float*)d_in[7];
    const float* b_g1    = (const float*)d_in[8];
    const float* dirs_g1 = (const float*)d_in[9];
    const float* W_g2    = (const float*)d_in[10];
    const float* b_g2    = (const float*)d_in[11];
    const float* dirs_g2 = (const float*)d_in[12];
    const float* g_l  = (const float*)d_in[13]; const float* be_l  = (const float*)d_in[14];
    const float* g_m0 = (const float*)d_in[15]; const float* be_m0 = (const float*)d_in[16];
    const float* g_m1 = (const float*)d_in[17]; const float* be_m1 = (const float*)d_in[18];
    const float* g_g0 = (const float*)d_in[19]; const float* be_g0 = (const float*)d_in[20];
    const float* g_g1 = (const float*)d_in[21]; const float* be_g1 = (const float*)d_in[22];
    const float* g_g2 = (const float*)d_in[23]; const float* be_g2 = (const float*)d_in[24];
    const float* W_down = (const float*)d_in[25];
    const float* b_down = (const float*)d_in[26];

    char* ws = (char*)d_ws;
    const size_t MB = 1 << 20;
    int*   idx100 = (int*)  (ws + 0);                 // 1.6384 MB
    float* st_l   = (float*)(ws + 0x1A0000);          // 6 stat blocks (a,b2)
    float* st_m0  = st_l + 256;
    float* st_m1  = st_l + 512;
    float* st_g0  = st_l + 768;
    float* st_g1  = st_l + 1024;
    float* st_g2  = st_l + 1280;
    float* nd100  = (float*)(ws +  2 * MB);           // 4.92 MB
    float* raw_l  = (float*)(ws +  8 * MB);           // 2 MB each
    float* raw_m0 = (float*)(ws + 10 * MB);
    float* raw_g0 = (float*)(ws + 12 * MB);
    float* raw_m1 = (float*)(ws + 14 * MB);
    float* raw_g1 = (float*)(ws + 16 * MB);
    float* raw_g2 = (float*)(ws + 18 * MB);
    float* fo_m   = (float*)(ws + 20 * MB);           // 4 MB each
    float* fo_g   = (float*)(ws + 24 * MB);
    float* fo_g2  = (float*)(ws + 28 * MB);
    // partials aliased into regions dead at their live range:
    double* p_l   = (double*)(ws + 28 * MB);  // live L2..L3 (fo_g2 written L7)
    double* p_m0  = (double*)(ws + 30 * MB);  // live L2..L3
    double* p_g0  = (double*)(ws + 20 * MB);  // live L2..L3 (fo_m written L4)
    double* p_m1  = (double*)(ws + 12 * MB);  // live L5..L6 (raw_g0 dead after L4)
    double* p_g1  = (double*)(ws + 13 * MB);  // live L5..L6
    double* p_g2  = (double*)(ws + 16 * MB);  // live L8..L9 (raw_g1 dead after L7)

    // L1. KNN + neighbor directions
    knn_kernel<<<1024, 256, 0, stream>>>(verts, idx100, nd100);
    // L2. surface convs (k=5/20/100) + BN partials
    surf3_kernel<<<1024, 128, 0, stream>>>(nd100, dirs_l, dirs_m0, dirs_g0,
                                           raw_l, raw_m0, raw_g0, p_l, p_m0, p_g0);
    // L3. finalize BN for l, m0, g0
    fin_kernel<<<384, 64, 0, stream>>>(p_l, g_l, be_l, st_l,
                                       p_m0, g_m0, be_m0, st_m0,
                                       p_g0, g_g0, be_g0, st_g0, 1024);
    // L4. fo_m = bn_relu(raw_m0) @ W_m1 ; fo_g = bn_relu(raw_g0) @ W_g1
    gemm2_kernel<<<dim3(256, 2), 256, 0, stream>>>(raw_m0, st_m0, W_m1, b_m1, fo_m,
                                                   raw_g0, st_g0, W_g1, b_g1, fo_g);
    // L5. conv-layer apply (m1: K=20, g1: K=100) + BN partials
    layer_kernel<<<dim3(512, 2), 128, 0, stream>>>(nd100, idx100,
                                                   dirs_m1, fo_m, raw_m1, 20, p_m1,
                                                   dirs_g1, fo_g, raw_g1, 100, p_g1);
    // L6. finalize BN for m1, g1
    fin_kernel<<<256, 64, 0, stream>>>(p_m1, g_m1, be_m1, st_m1,
                                       p_g1, g_g1, be_g1, st_g1,
                                       p_g1, g_g1, be_g1, st_g1, 512);
    // L7. fo_g2 = bn_relu(raw_g1) @ W_g2
    gemm2_kernel<<<dim3(256, 1), 256, 0, stream>>>(raw_g1, st_g1, W_g2, b_g2, fo_g2,
                                                   raw_g1, st_g1, W_g2, b_g2, fo_g2);
    // L8. conv-layer apply (g2: K=100) + BN partials
    layer_kernel<<<dim3(512, 1), 128, 0, stream>>>(nd100, idx100,
                                                   dirs_g2, fo_g2, raw_g2, 100, p_g2,
                                                   dirs_g2, fo_g2, raw_g2, 100, p_g2);
    // L9. finalize BN for g2
    fin_kernel<<<128, 64, 0, stream>>>(p_g2, g_g2, be_g2, st_g2,
                                       p_g2, g_g2, be_g2, st_g2,
                                       p_g2, g_g2, be_g2, st_g2, 512);
    // L10. final: relu(concat(bn_relu each) @ W_down + b_down) -> fp32 out
    gemmf_kernel<<<256, 256, 0, stream>>>(raw_l, raw_m1, raw_g2,
                                          st_l, st_m1, st_g2,
                                          W_down, b_down, (float*)d_out);
}

// Round 6
// 403.518 us; speedup vs baseline: 1.3210x; 1.3210x over previous
//
#include <hip/hip_runtime.h>
#include <math.h>

typedef unsigned long long u64;

// ---------------------------------------------------------------------------
// Kernel 1: KNN, bit-exact vs the np/fp32 reference. Keys pack (monotone
// fp32 dist, idx) into one u64; per lane 16 candidates bitonic-sorted once;
// extraction = u64 min-butterfly + winner shift-pop. One wave per row.
// ---------------------------------------------------------------------------
__global__ __launch_bounds__(256) void knn_kernel(const float* __restrict__ verts,
                                                  int* __restrict__ idx_out,
                                                  float* __restrict__ nd_out)
{
    __shared__ float vx[1024], vy[1024], vz[1024], sq[1024];
    const int tid = threadIdx.x;
    const int row0 = blockIdx.x * 4;
    const int b = row0 >> 10;            // block never crosses a batch
    const float* vb = verts + b * 3072;

    for (int t = tid; t < 3072; t += 256) {
        float v = vb[t];
        int n = t / 3, c = t - n * 3;
        if (c == 0) vx[n] = v; else if (c == 1) vy[n] = v; else vz[n] = v;
    }
    __syncthreads();
    for (int n = tid; n < 1024; n += 256) {
        float x = vx[n], y = vy[n], z = vz[n];
        sq[n] = __fadd_rn(__fadd_rn(__fmul_rn(x, x), __fmul_rn(y, y)),
                          __fmul_rn(z, z));
    }
    __syncthreads();

    const int w = tid >> 6, lane = tid & 63;
    const int row = row0 + w;
    const int n_i = row & 1023;
    const float xi = vx[n_i], yi = vy[n_i], zi = vz[n_i];
    const float sqi = sq[n_i];

    u64 K[16];
#pragma unroll
    for (int t = 0; t < 16; ++t) {
        int j = t * 64 + lane;
        float dot = __fadd_rn(__fadd_rn(__fmul_rn(xi, vx[j]),
                                        __fmul_rn(yi, vy[j])),
                              __fmul_rn(zi, vz[j]));
        float d = __fsub_rn(__fadd_rn(sqi, sq[j]), __fmul_rn(2.0f, dot));
        d = __fadd_rn(d, 0.0f);          // canonicalize -0.0 -> +0.0
        unsigned u = __float_as_uint(d);
        unsigned m = (u & 0x80000000u) ? ~u : (u | 0x80000000u);
        K[t] = ((u64)m << 10) | (unsigned)j;
    }

    // in-register bitonic sort, ascending (keys unique -> stable by idx)
#pragma unroll
    for (int k2 = 2; k2 <= 16; k2 <<= 1)
#pragma unroll
        for (int jj = k2 >> 1; jj > 0; jj >>= 1)
#pragma unroll
            for (int i = 0; i < 16; ++i) {
                int l = i ^ jj;
                if (l > i) {
                    bool up = ((i & k2) == 0);
                    bool sw = up ? (K[i] > K[l]) : (K[i] < K[l]);
                    u64 a = K[i], c = K[l];
                    K[i] = sw ? c : a;
                    K[l] = sw ? a : c;
                }
            }

    unsigned s0 = 0, s1 = 0;
    for (int it = 0; it < 101; ++it) {
        u64 bk = K[0];
#pragma unroll
        for (int off = 1; off < 64; off <<= 1) {
            u64 ok = __shfl_xor(bk, off);
            if (ok < bk) bk = ok;
        }
        unsigned j = (unsigned)bk & 1023u;
        if ((int)(j & 63u) == lane) {    // winner pops its head
#pragma unroll
            for (int t = 0; t < 15; ++t) K[t] = K[t + 1];
            K[15] = ~0ULL;
        }
        if (it == lane)      s0 = j;
        if (it == 64 + lane) s1 = j;
    }

    // parallel epilogue: lane L writes ranks L and 64+L (rank 0 dropped)
    const int rowbase = row & ~1023;
#pragma unroll
    for (int e = 0; e < 2; ++e) {
        int itv = lane + 64 * e;
        unsigned j = e ? s1 : s0;
        if (itv >= 1 && itv <= 100) {
            int slot = itv - 1;
            idx_out[row * 100 + slot] = rowbase + (int)j;
            float dx = vx[j] - xi, dy = vy[j] - yi, dz = vz[j] - zi;
            float nrm = sqrtf(__fadd_rn(__fadd_rn(__fmul_rn(dx, dx),
                                                  __fmul_rn(dy, dy)),
                                        __fmul_rn(dz, dz)));
            float inv = 1.0f / fmaxf(nrm, 1e-12f);
            float* o = nd_out + (row * 100 + slot) * 3;
            o[0] = dx * inv; o[1] = dy * inv; o[2] = dz * inv;
        }
    }
}

// ---------------------------------------------------------------------------
// Kernel 2: fused surface conv, 3 scales (k=5/20/100 prefixes). One row per
// 128-thread block (max occupancy); thread d = channel d.
// ---------------------------------------------------------------------------
__global__ __launch_bounds__(128) void surf3_kernel(const float* __restrict__ nd,
    const float* __restrict__ dl, const float* __restrict__ dm, const float* __restrict__ dg,
    float* __restrict__ raw_l, float* __restrict__ raw_m, float* __restrict__ raw_g)
{
    __shared__ float nds[300];
    const int d = threadIdx.x;
    const int row = blockIdx.x;

    float lx = dl[d], ly = dl[128 + d], lz = dl[256 + d];
    float li = 1.0f / fmaxf(sqrtf((lx * lx + ly * ly) + lz * lz), 1e-12f);
    lx *= li; ly *= li; lz *= li;
    float mx = dm[d], my = dm[128 + d], mz = dm[256 + d];
    float mi = 1.0f / fmaxf(sqrtf((mx * mx + my * my) + mz * mz), 1e-12f);
    mx *= mi; my *= mi; mz *= mi;
    float gx = dg[d], gy = dg[128 + d], gz = dg[256 + d];
    float gi = 1.0f / fmaxf(sqrtf((gx * gx + gy * gy) + gz * gz), 1e-12f);
    gx *= gi; gy *= gi; gz *= gi;

    for (int t = d; t < 300; t += 128) nds[t] = nd[row * 300 + t];
    __syncthreads();

    float ml = -1e30f, mm = -1e30f, mg = -1e30f;
    for (int k = 0; k < 100; ++k) {
        float x = nds[3 * k], y = nds[3 * k + 1], z = nds[3 * k + 2];
        mg = fmaxf(mg, (x * gx + y * gy) + z * gz);
        if (k < 20) mm = fmaxf(mm, (x * mx + y * my) + z * mz);
        if (k < 5)  ml = fmaxf(ml, (x * lx + y * ly) + z * lz);
    }
    raw_l[row * 128 + d] = fmaxf(ml, 0.0f);
    raw_m[row * 128 + d] = fmaxf(mm, 0.0f);
    raw_g[row * 128 + d] = fmaxf(mg, 0.0f);
}

// ---------------------------------------------------------------------------
// Kernel 3: BN stats, coalesced: one 1024-thread block per tensor. Thread
// (seg=t>>7, c=t&127) streams rows seg*512..seg*512+511 of src[4096][128]
// (consecutive threads -> consecutive addresses), fp64 accumulate, LDS
// reduce over segs. st[c]=a, st[128+c]=b2 with bn_relu(x)=relu(a*x+b2).
// ---------------------------------------------------------------------------
__global__ __launch_bounds__(1024) void fin_kernel(
    const float* s0, const float* g0, const float* e0, float* st0,
    const float* s1, const float* g1, const float* e1, float* st1,
    const float* s2, const float* g2, const float* e2, float* st2)
{
    const int t = blockIdx.x;
    const float* src = (t == 0) ? s0 : (t == 1) ? s1 : s2;
    const float* g = (t == 0) ? g0 : (t == 1) ? g1 : g2;
    const float* e = (t == 0) ? e0 : (t == 1) ? e1 : e2;
    float* st = (t == 0) ? st0 : (t == 1) ? st1 : st2;

    const int tid = threadIdx.x;
    const int c = tid & 127, seg = tid >> 7;      // 8 segments x 512 rows
    double s = 0.0, q = 0.0;
    const float* p = src + (size_t)seg * 512 * 128 + c;
    for (int r = 0; r < 512; ++r) {
        float v = p[r * 128];
        s += v; q += (double)v * v;
    }
    __shared__ double Ls[8][128], Lq[8][128];
    Ls[seg][c] = s; Lq[seg][c] = q;
    __syncthreads();
    if (tid < 128) {
        double S = 0.0, Q = 0.0;
#pragma unroll
        for (int i = 0; i < 8; ++i) { S += Ls[i][tid]; Q += Lq[i][tid]; }
        double m = S * (1.0 / 4096.0);
        double var = Q * (1.0 / 4096.0) - m * m;
        double a = (double)g[tid] / sqrt(var + 1e-5);
        st[tid] = (float)a;
        st[128 + tid] = (float)((double)e[tid] - m * a);
    }
}

// ---------------------------------------------------------------------------
// Kernel 4: dual-job GEMM (CIN=128): out[r][o] = bias[o] + sum_c bn_relu(A) W
// ---------------------------------------------------------------------------
__global__ __launch_bounds__(256) void gemm2_kernel(
    const float* __restrict__ Aa, const float* __restrict__ sta,
    const float* __restrict__ Wa, const float* __restrict__ ba, float* __restrict__ outa,
    const float* __restrict__ Ab, const float* __restrict__ stb,
    const float* __restrict__ Wb, const float* __restrict__ bb, float* __restrict__ outb)
{
    const int job = blockIdx.y;
    const float* A = job ? Ab : Aa;  const float* st = job ? stb : sta;
    const float* W = job ? Wb : Wa;  const float* bias = job ? bb : ba;
    float* out = job ? outb : outa;

    __shared__ float As[16 * 128];
    const int o = threadIdx.x;
    const int r0 = blockIdx.x * 16;

    for (int t = o; t < 16 * 128; t += 256) {
        int r = t >> 7, c = t & 127;
        As[t] = fmaxf(fmaf(st[c], A[(r0 + r) * 128 + c], st[128 + c]), 0.0f);
    }
    __syncthreads();

    float acc[16];
    const float bz = bias[o];
#pragma unroll
    for (int r = 0; r < 16; ++r) acc[r] = bz;

    for (int c = 0; c < 128; c += 4) {
        float w0 = W[(c + 0) * 256 + o];
        float w1 = W[(c + 1) * 256 + o];
        float w2 = W[(c + 2) * 256 + o];
        float w3 = W[(c + 3) * 256 + o];
#pragma unroll
        for (int r = 0; r < 16; ++r) {
            const float4 av = *(const float4*)&As[r * 128 + c];
            acc[r] += av.x * w0 + av.y * w1 + av.z * w2 + av.w * w3;
        }
    }
#pragma unroll
    for (int r = 0; r < 16; ++r)
        out[(r0 + r) * 256 + o] = acc[r];
}

// ---------------------------------------------------------------------------
// Kernel 5: conv-layer apply, 1 row per 128-thread block (max occupancy),
// up to 2 jobs via blockIdx.y.
// out[r][d] = fo[r][d] + max_k relu(nd_k . ndir_d) * fo[idx_k][128+d]
// ---------------------------------------------------------------------------
__global__ __launch_bounds__(128) void layer_kernel(
    const float* __restrict__ nd, const int* __restrict__ idxbuf,
    const float* dir0, const float* fo0, float* out0, int K0,
    const float* dir1, const float* fo1, float* out1, int K1)
{
    const int job = blockIdx.y;
    const float* dirs = job ? dir1 : dir0;
    const float* fo = job ? fo1 : fo0;
    float* out = job ? out1 : out0;
    const int K = job ? K1 : K0;

    __shared__ float nds[300];
    __shared__ int idxs[100];
    const int d = threadIdx.x;
    const int row = blockIdx.x;

    float dx = dirs[d], dy = dirs[128 + d], dz = dirs[256 + d];
    float di = 1.0f / fmaxf(sqrtf((dx * dx + dy * dy) + dz * dz), 1e-12f);
    dx *= di; dy *= di; dz *= di;

    for (int t = d; t < K * 3; t += 128) nds[t] = nd[row * 300 + t];
    if (d < K) idxs[d] = idxbuf[row * 100 + d];
    __syncthreads();

    float acc = -1e30f;
    for (int k = 0; k < K; ++k) {
        float th = fmaxf((nds[3 * k] * dx + nds[3 * k + 1] * dy) + nds[3 * k + 2] * dz, 0.0f);
        float fs = fo[idxs[k] * 256 + 128 + d];   // global row index
        acc = fmaxf(acc, th * fs);
    }
    out[row * 128 + d] = fo[row * 256 + d] + acc;
}

// ---------------------------------------------------------------------------
// Kernel 6: final GEMM (CIN=384 from 3 bn_relu'd segments) + relu, fp32 out.
// ---------------------------------------------------------------------------
__global__ __launch_bounds__(256) void gemmf_kernel(
    const float* __restrict__ A0, const float* __restrict__ A1, const float* __restrict__ A2,
    const float* __restrict__ st0, const float* __restrict__ st1, const float* __restrict__ st2,
    const float* __restrict__ W, const float* __restrict__ bias, float* __restrict__ out)
{
    __shared__ float As[16 * 384];
    const int o = threadIdx.x;
    const int r0 = blockIdx.x * 16;

    for (int t = o; t < 16 * 384; t += 256) {
        int r = t / 384, c = t - r * 384;
        int seg = c >> 7, cc = c & 127;
        const float* A = (seg == 0) ? A0 : (seg == 1) ? A1 : A2;
        const float* st = (seg == 0) ? st0 : (seg == 1) ? st1 : st2;
        As[t] = fmaxf(fmaf(st[cc], A[(r0 + r) * 128 + cc], st[128 + cc]), 0.0f);
    }
    __syncthreads();

    float acc[16];
    const float bz = bias[o];
#pragma unroll
    for (int r = 0; r < 16; ++r) acc[r] = bz;

    for (int c = 0; c < 384; c += 4) {
        float w0 = W[(c + 0) * 256 + o];
        float w1 = W[(c + 1) * 256 + o];
        float w2 = W[(c + 2) * 256 + o];
        float w3 = W[(c + 3) * 256 + o];
#pragma unroll
        for (int r = 0; r < 16; ++r) {
            const float4 av = *(const float4*)&As[r * 384 + c];
            acc[r] += av.x * w0 + av.y * w1 + av.z * w2 + av.w * w3;
        }
    }
#pragma unroll
    for (int r = 0; r < 16; ++r)
        out[(r0 + r) * 256 + o] = fmaxf(acc[r], 0.0f);
}

// ---------------------------------------------------------------------------
extern "C" void kernel_launch(void* const* d_in, const int* in_sizes, int n_in,
                              void* d_out, int out_size, void* d_ws, size_t ws_size,
                              hipStream_t stream)
{
    (void)in_sizes; (void)n_in; (void)out_size; (void)ws_size;

    const float* verts   = (const float*)d_in[0];
    const float* dirs_l  = (const float*)d_in[1];
    const float* dirs_m0 = (const float*)d_in[2];
    const float* W_m1    = (const float*)d_in[3];
    const float* b_m1    = (const float*)d_in[4];
    const float* dirs_m1 = (const float*)d_in[5];
    const float* dirs_g0 = (const float*)d_in[6];
    const float* W_g1    = (const float*)d_in[7];
    const float* b_g1    = (const float*)d_in[8];
    const float* dirs_g1 = (const float*)d_in[9];
    const float* W_g2    = (const float*)d_in[10];
    const float* b_g2    = (const float*)d_in[11];
    const float* dirs_g2 = (const float*)d_in[12];
    const float* g_l  = (const float*)d_in[13]; const float* be_l  = (const float*)d_in[14];
    const float* g_m0 = (const float*)d_in[15]; const float* be_m0 = (const float*)d_in[16];
    const float* g_m1 = (const float*)d_in[17]; const float* be_m1 = (const float*)d_in[18];
    const float* g_g0 = (const float*)d_in[19]; const float* be_g0 = (const float*)d_in[20];
    const float* g_g1 = (const float*)d_in[21]; const float* be_g1 = (const float*)d_in[22];
    const float* g_g2 = (const float*)d_in[23]; const float* be_g2 = (const float*)d_in[24];
    const float* W_down = (const float*)d_in[25];
    const float* b_down = (const float*)d_in[26];

    char* ws = (char*)d_ws;
    const size_t MB = 1 << 20;
    int*   idx100 = (int*)  (ws + 0);                 // 1.64 MB
    float* st_l   = (float*)(ws + 0x1A0000);          // 6 stat blocks (a,b2)
    float* st_m0  = st_l + 256;
    float* st_m1  = st_l + 512;
    float* st_g0  = st_l + 768;
    float* st_g1  = st_l + 1024;
    float* st_g2  = st_l + 1280;
    float* nd100  = (float*)(ws +  2 * MB);           // 4.92 MB
    float* raw_l  = (float*)(ws +  8 * MB);           // 2 MB each
    float* raw_m0 = (float*)(ws + 10 * MB);
    float* raw_g0 = (float*)(ws + 12 * MB);
    float* raw_m1 = (float*)(ws + 14 * MB);
    float* raw_g1 = (float*)(ws + 16 * MB);
    float* raw_g2 = (float*)(ws + 18 * MB);
    float* fo_m   = (float*)(ws + 20 * MB);           // 4 MB each
    float* fo_g   = (float*)(ws + 24 * MB);
    float* fo_g2  = (float*)(ws + 28 * MB);

    // L1. KNN + neighbor directions
    knn_kernel<<<1024, 256, 0, stream>>>(verts, idx100, nd100);
    // L2. surface convs (k=5/20/100)
    surf3_kernel<<<4096, 128, 0, stream>>>(nd100, dirs_l, dirs_m0, dirs_g0,
                                           raw_l, raw_m0, raw_g0);
    // L3. BN stats for l, m0, g0
    fin_kernel<<<3, 1024, 0, stream>>>(raw_l, g_l, be_l, st_l,
                                       raw_m0, g_m0, be_m0, st_m0,
                                       raw_g0, g_g0, be_g0, st_g0);
    // L4. fo_m = bn_relu(raw_m0) @ W_m1 ; fo_g = bn_relu(raw_g0) @ W_g1
    gemm2_kernel<<<dim3(256, 2), 256, 0, stream>>>(raw_m0, st_m0, W_m1, b_m1, fo_m,
                                                   raw_g0, st_g0, W_g1, b_g1, fo_g);
    // L5. conv-layer apply (m1: K=20, g1: K=100)
    layer_kernel<<<dim3(4096, 2), 128, 0, stream>>>(nd100, idx100,
                                                    dirs_m1, fo_m, raw_m1, 20,
                                                    dirs_g1, fo_g, raw_g1, 100);
    // L6. BN stats for m1, g1
    fin_kernel<<<2, 1024, 0, stream>>>(raw_m1, g_m1, be_m1, st_m1,
                                       raw_g1, g_g1, be_g1, st_g1,
                                       raw_g1, g_g1, be_g1, st_g1);
    // L7. fo_g2 = bn_relu(raw_g1) @ W_g2
    gemm2_kernel<<<dim3(256, 1), 256, 0, stream>>>(raw_g1, st_g1, W_g2, b_g2, fo_g2,
                                                   raw_g1, st_g1, W_g2, b_g2, fo_g2);
    // L8. conv-layer apply (g2: K=100)
    layer_kernel<<<dim3(4096, 1), 128, 0, stream>>>(nd100, idx100,
                                                    dirs_g2, fo_g2, raw_g2, 100,
                                                    dirs_g2, fo_g2, raw_g2, 100);
    // L9. BN stats for g2
    fin_kernel<<<1, 1024, 0, stream>>>(raw_g2, g_g2, be_g2, st_g2,
                                       raw_g2, g_g2, be_g2, st_g2,
                                       raw_g2, g_g2, be_g2, st_g2);
    // L10. final: relu(concat(bn_relu each) @ W_down + b_down) -> fp32 out
    gemmf_kernel<<<256, 256, 0, stream>>>(raw_l, raw_m1, raw_g2,
                                          st_l, st_m1, st_g2,
                                          W_down, b_down, (float*)d_out);
}

// Round 7
// 372.726 us; speedup vs baseline: 1.4301x; 1.0826x over previous
//
#include <hip/hip_runtime.h>
#include <math.h>

typedef unsigned long long u64;

// ---------------------------------------------------------------------------
// Kernel 1: KNN, bit-exact vs the np/fp32 reference.
// Keys: (monotone fp32 dist << 10) | idx  (unique). Algorithm:
//   1) bisect threshold T until count(key<T) in [101,320]  (exists; <=42 iters)
//   2) compact candidates <T into LDS via wave prefix-scan
//   3) brute-force exact ranks within the compacted set
//   4) rank 0 dropped; ranks 1..100 -> slot rank-1 (exact stable-top_k order)
// One wave per row, 4 rows per 256-thread block.
// ---------------------------------------------------------------------------
__global__ __launch_bounds__(256) void knn_kernel(const float* __restrict__ verts,
                                                  int* __restrict__ idx_out,
                                                  float* __restrict__ nd_out)
{
    __shared__ float vx[1024], vy[1024], vz[1024], sq[1024];
    __shared__ u64 cand[4][320];
    const int tid = threadIdx.x;
    const int row0 = blockIdx.x * 4;
    const int b = row0 >> 10;            // block never crosses a batch
    const float* vb = verts + b * 3072;

    for (int t = tid; t < 3072; t += 256) {
        float v = vb[t];
        int n = t / 3, c = t - n * 3;
        if (c == 0) vx[n] = v; else if (c == 1) vy[n] = v; else vz[n] = v;
    }
    __syncthreads();
    for (int n = tid; n < 1024; n += 256) {
        float x = vx[n], y = vy[n], z = vz[n];
        sq[n] = __fadd_rn(__fadd_rn(__fmul_rn(x, x), __fmul_rn(y, y)),
                          __fmul_rn(z, z));
    }
    __syncthreads();

    const int w = tid >> 6, lane = tid & 63;
    const int row = row0 + w;
    const int n_i = row & 1023;
    const float xi = vx[n_i], yi = vy[n_i], zi = vz[n_i];
    const float sqi = sq[n_i];

    u64 K[16];
#pragma unroll
    for (int t = 0; t < 16; ++t) {
        int j = t * 64 + lane;
        float dot = __fadd_rn(__fadd_rn(__fmul_rn(xi, vx[j]),
                                        __fmul_rn(yi, vy[j])),
                              __fmul_rn(zi, vz[j]));
        float d = __fsub_rn(__fadd_rn(sqi, sq[j]), __fmul_rn(2.0f, dot));
        d = __fadd_rn(d, 0.0f);          // canonicalize -0.0 -> +0.0
        unsigned u = __float_as_uint(d);
        unsigned m = (u & 0x80000000u) ? ~u : (u | 0x80000000u);
        K[t] = ((u64)m << 10) | (unsigned)j;
    }

    // --- 1) bisect threshold: count(key < hi) in [101, 320] ---
    u64 lo = 0, hi = 1ULL << 42;
    int chi = 1024;                      // count(key < 2^42) == 1024
    while (chi > 320) {
        u64 mid = (lo + hi) >> 1;
        int c = 0;
#pragma unroll
        for (int t = 0; t < 16; ++t) c += (K[t] < mid) ? 1 : 0;
#pragma unroll
        for (int off = 1; off < 64; off <<= 1) c += __shfl_xor(c, off);
        if (c >= 101) { hi = mid; chi = c; } else lo = mid;
    }
    const u64 T = hi;
    const int n = chi;                   // 101 <= n <= 320

    // --- 2) compact candidates < T via wave prefix-scan ---
    int myc_n = 0;
#pragma unroll
    for (int t = 0; t < 16; ++t) myc_n += (K[t] < T) ? 1 : 0;
    int sc = myc_n;
#pragma unroll
    for (int off = 1; off < 64; off <<= 1) {
        int v = __shfl_up(sc, off);
        if (lane >= off) sc += v;
    }
    int pos = sc - myc_n;                // exclusive prefix
#pragma unroll
    for (int t = 0; t < 16; ++t) {
        if (K[t] < T) cand[w][pos++] = K[t];
    }
    __syncthreads();                     // order LDS writes before reads

    // --- 3) exact ranks within compacted set ---
    u64 myc[5]; int rk[5];
#pragma unroll
    for (int q = 0; q < 5; ++q) {
        int i = lane + q * 64;
        myc[q] = (i < n) ? cand[w][i] : ~0ULL;
        rk[q] = 0;
    }
    for (int jj = 0; jj < n; ++jj) {
        u64 kk = cand[w][jj];            // broadcast read
#pragma unroll
        for (int q = 0; q < 5; ++q) rk[q] += (kk < myc[q]) ? 1 : 0;
    }

    // --- 4) write ranks 1..100 (rank 0 = self/top dropped) ---
    const int rowbase = row & ~1023;
#pragma unroll
    for (int q = 0; q < 5; ++q) {
        int i = lane + q * 64;
        if (i < n) {
            int r = rk[q];
            if (r >= 1 && r <= 100) {
                int slot = r - 1;
                unsigned j = (unsigned)(myc[q] & 1023u);
                idx_out[row * 100 + slot] = rowbase + (int)j;
                float dx = vx[j] - xi, dy = vy[j] - yi, dz = vz[j] - zi;
                float nrm = sqrtf(__fadd_rn(__fadd_rn(__fmul_rn(dx, dx),
                                                      __fmul_rn(dy, dy)),
                                            __fmul_rn(dz, dz)));
                float inv = 1.0f / fmaxf(nrm, 1e-12f);
                float* o = nd_out + (row * 100 + slot) * 3;
                o[0] = dx * inv; o[1] = dy * inv; o[2] = dz * inv;
            }
        }
    }
}

// ---------------------------------------------------------------------------
// Kernel 2: fused surface conv, 3 scales (k=5/20/100 prefixes). One row per
// 128-thread block; thread d = channel d. nd reads are wave-uniform ->
// scalar loads (no LDS).
// ---------------------------------------------------------------------------
__global__ __launch_bounds__(128) void surf3_kernel(const float* __restrict__ nd,
    const float* __restrict__ dl, const float* __restrict__ dm, const float* __restrict__ dg,
    float* __restrict__ raw_l, float* __restrict__ raw_m, float* __restrict__ raw_g)
{
    const int d = threadIdx.x;
    const int row = blockIdx.x;

    float lx = dl[d], ly = dl[128 + d], lz = dl[256 + d];
    float li = 1.0f / fmaxf(sqrtf((lx * lx + ly * ly) + lz * lz), 1e-12f);
    lx *= li; ly *= li; lz *= li;
    float mx = dm[d], my = dm[128 + d], mz = dm[256 + d];
    float mi = 1.0f / fmaxf(sqrtf((mx * mx + my * my) + mz * mz), 1e-12f);
    mx *= mi; my *= mi; mz *= mi;
    float gx = dg[d], gy = dg[128 + d], gz = dg[256 + d];
    float gi = 1.0f / fmaxf(sqrtf((gx * gx + gy * gy) + gz * gz), 1e-12f);
    gx *= gi; gy *= gi; gz *= gi;

    const float* ns = nd + (size_t)row * 300;
    float ml = -1e30f, mm = -1e30f, mg = -1e30f;
    int k = 0;
    for (; k < 5; ++k) {
        float x = ns[3 * k], y = ns[3 * k + 1], z = ns[3 * k + 2];
        ml = fmaxf(ml, (x * lx + y * ly) + z * lz);
        mm = fmaxf(mm, (x * mx + y * my) + z * mz);
        mg = fmaxf(mg, (x * gx + y * gy) + z * gz);
    }
    for (; k < 20; ++k) {
        float x = ns[3 * k], y = ns[3 * k + 1], z = ns[3 * k + 2];
        mm = fmaxf(mm, (x * mx + y * my) + z * mz);
        mg = fmaxf(mg, (x * gx + y * gy) + z * gz);
    }
    for (; k < 100; ++k) {
        float x = ns[3 * k], y = ns[3 * k + 1], z = ns[3 * k + 2];
        mg = fmaxf(mg, (x * gx + y * gy) + z * gz);
    }
    raw_l[row * 128 + d] = fmaxf(ml, 0.0f);
    raw_m[row * 128 + d] = fmaxf(mm, 0.0f);
    raw_g[row * 128 + d] = fmaxf(mg, 0.0f);
}

// ---------------------------------------------------------------------------
// Kernel 3: BN stats, coalesced: one 1024-thread block per tensor.
// st[c]=a, st[128+c]=b2 with bn_relu(x)=relu(a*x+b2).
// ---------------------------------------------------------------------------
__global__ __launch_bounds__(1024) void fin_kernel(
    const float* s0, const float* g0, const float* e0, float* st0,
    const float* s1, const float* g1, const float* e1, float* st1,
    const float* s2, const float* g2, const float* e2, float* st2)
{
    const int t = blockIdx.x;
    const float* src = (t == 0) ? s0 : (t == 1) ? s1 : s2;
    const float* g = (t == 0) ? g0 : (t == 1) ? g1 : g2;
    const float* e = (t == 0) ? e0 : (t == 1) ? e1 : e2;
    float* st = (t == 0) ? st0 : (t == 1) ? st1 : st2;

    const int tid = threadIdx.x;
    const int c = tid & 127, seg = tid >> 7;      // 8 segments x 512 rows
    double s = 0.0, q = 0.0;
    const float* p = src + (size_t)seg * 512 * 128 + c;
    for (int r = 0; r < 512; ++r) {
        float v = p[r * 128];
        s += v; q += (double)v * v;
    }
    __shared__ double Ls[8][128], Lq[8][128];
    Ls[seg][c] = s; Lq[seg][c] = q;
    __syncthreads();
    if (tid < 128) {
        double S = 0.0, Q = 0.0;
#pragma unroll
        for (int i = 0; i < 8; ++i) { S += Ls[i][tid]; Q += Lq[i][tid]; }
        double m = S * (1.0 / 4096.0);
        double var = Q * (1.0 / 4096.0) - m * m;
        double a = (double)g[tid] / sqrt(var + 1e-5);
        st[tid] = (float)a;
        st[128 + tid] = (float)((double)e[tid] - m * a);
    }
}

// ---------------------------------------------------------------------------
// Kernel 4: dual-job GEMM (CIN=128): out[r][o] = bias[o] + sum_c bn_relu(A) W
// ---------------------------------------------------------------------------
__global__ __launch_bounds__(256) void gemm2_kernel(
    const float* __restrict__ Aa, const float* __restrict__ sta,
    const float* __restrict__ Wa, const float* __restrict__ ba, float* __restrict__ outa,
    const float* __restrict__ Ab, const float* __restrict__ stb,
    const float* __restrict__ Wb, const float* __restrict__ bb, float* __restrict__ outb)
{
    const int job = blockIdx.y;
    const float* A = job ? Ab : Aa;  const float* st = job ? stb : sta;
    const float* W = job ? Wb : Wa;  const float* bias = job ? bb : ba;
    float* out = job ? outb : outa;

    __shared__ float As[16 * 128];
    const int o = threadIdx.x;
    const int r0 = blockIdx.x * 16;

    for (int t = o; t < 16 * 128; t += 256) {
        int r = t >> 7, c = t & 127;
        As[t] = fmaxf(fmaf(st[c], A[(r0 + r) * 128 + c], st[128 + c]), 0.0f);
    }
    __syncthreads();

    float acc[16];
    const float bz = bias[o];
#pragma unroll
    for (int r = 0; r < 16; ++r) acc[r] = bz;

    for (int c = 0; c < 128; c += 4) {
        float w0 = W[(c + 0) * 256 + o];
        float w1 = W[(c + 1) * 256 + o];
        float w2 = W[(c + 2) * 256 + o];
        float w3 = W[(c + 3) * 256 + o];
#pragma unroll
        for (int r = 0; r < 16; ++r) {
            const float4 av = *(const float4*)&As[r * 128 + c];
            acc[r] += av.x * w0 + av.y * w1 + av.z * w2 + av.w * w3;
        }
    }
#pragma unroll
    for (int r = 0; r < 16; ++r)
        out[(r0 + r) * 256 + o] = acc[r];
}

// ---------------------------------------------------------------------------
// Kernel 5: conv-layer apply, 1 row per 128-thread block, up to 2 jobs via
// blockIdx.y. nd/idx reads wave-uniform -> scalar loads (no LDS).
// out[r][d] = fo[r][d] + max_k relu(nd_k . ndir_d) * fo[idx_k][128+d]
// ---------------------------------------------------------------------------
__global__ __launch_bounds__(128) void layer_kernel(
    const float* __restrict__ nd, const int* __restrict__ idxbuf,
    const float* dir0, const float* fo0, float* out0, int K0,
    const float* dir1, const float* fo1, float* out1, int K1)
{
    const int job = blockIdx.y;
    const float* dirs = job ? dir1 : dir0;
    const float* fo = job ? fo1 : fo0;
    float* out = job ? out1 : out0;
    const int K = job ? K1 : K0;

    const int d = threadIdx.x;
    const int row = blockIdx.x;

    float dx = dirs[d], dy = dirs[128 + d], dz = dirs[256 + d];
    float di = 1.0f / fmaxf(sqrtf((dx * dx + dy * dy) + dz * dz), 1e-12f);
    dx *= di; dy *= di; dz *= di;

    const float* ns = nd + (size_t)row * 300;
    const int* ib = idxbuf + (size_t)row * 100;

    float acc = -1e30f;
    for (int k = 0; k < K; ++k) {
        float x = ns[3 * k], y = ns[3 * k + 1], z = ns[3 * k + 2];
        int ix = ib[k];
        float th = fmaxf((x * dx + y * dy) + z * dz, 0.0f);
        float fs = fo[ix * 256 + 128 + d];   // global row index, coalesced
        acc = fmaxf(acc, th * fs);
    }
    out[row * 128 + d] = fo[row * 256 + d] + acc;
}

// ---------------------------------------------------------------------------
// Kernel 6: final GEMM (CIN=384 from 3 bn_relu'd segments) + relu, fp32 out.
// ---------------------------------------------------------------------------
__global__ __launch_bounds__(256) void gemmf_kernel(
    const float* __restrict__ A0, const float* __restrict__ A1, const float* __restrict__ A2,
    const float* __restrict__ st0, const float* __restrict__ st1, const float* __restrict__ st2,
    const float* __restrict__ W, const float* __restrict__ bias, float* __restrict__ out)
{
    __shared__ float As[16 * 384];
    const int o = threadIdx.x;
    const int r0 = blockIdx.x * 16;

    for (int t = o; t < 16 * 384; t += 256) {
        int r = t / 384, c = t - r * 384;
        int seg = c >> 7, cc = c & 127;
        const float* A = (seg == 0) ? A0 : (seg == 1) ? A1 : A2;
        const float* st = (seg == 0) ? st0 : (seg == 1) ? st1 : st2;
        As[t] = fmaxf(fmaf(st[cc], A[(r0 + r) * 128 + cc], st[128 + cc]), 0.0f);
    }
    __syncthreads();

    float acc[16];
    const float bz = bias[o];
#pragma unroll
    for (int r = 0; r < 16; ++r) acc[r] = bz;

    for (int c = 0; c < 384; c += 4) {
        float w0 = W[(c + 0) * 256 + o];
        float w1 = W[(c + 1) * 256 + o];
        float w2 = W[(c + 2) * 256 + o];
        float w3 = W[(c + 3) * 256 + o];
#pragma unroll
        for (int r = 0; r < 16; ++r) {
            const float4 av = *(const float4*)&As[r * 384 + c];
            acc[r] += av.x * w0 + av.y * w1 + av.z * w2 + av.w * w3;
        }
    }
#pragma unroll
    for (int r = 0; r < 16; ++r)
        out[(r0 + r) * 256 + o] = fmaxf(acc[r], 0.0f);
}

// ---------------------------------------------------------------------------
extern "C" void kernel_launch(void* const* d_in, const int* in_sizes, int n_in,
                              void* d_out, int out_size, void* d_ws, size_t ws_size,
                              hipStream_t stream)
{
    (void)in_sizes; (void)n_in; (void)out_size; (void)ws_size;

    const float* verts   = (const float*)d_in[0];
    const float* dirs_l  = (const float*)d_in[1];
    const float* dirs_m0 = (const float*)d_in[2];
    const float* W_m1    = (const float*)d_in[3];
    const float* b_m1    = (const float*)d_in[4];
    const float* dirs_m1 = (const float*)d_in[5];
    const float* dirs_g0 = (const float*)d_in[6];
    const float* W_g1    = (const float*)d_in[7];
    const float* b_g1    = (const float*)d_in[8];
    const float* dirs_g1 = (const float*)d_in[9];
    const float* W_g2    = (const float*)d_in[10];
    const float* b_g2    = (const float*)d_in[11];
    const float* dirs_g2 = (const float*)d_in[12];
    const float* g_l  = (const float*)d_in[13]; const float* be_l  = (const float*)d_in[14];
    const float* g_m0 = (const float*)d_in[15]; const float* be_m0 = (const float*)d_in[16];
    const float* g_m1 = (const float*)d_in[17]; const float* be_m1 = (const float*)d_in[18];
    const float* g_g0 = (const float*)d_in[19]; const float* be_g0 = (const float*)d_in[20];
    const float* g_g1 = (const float*)d_in[21]; const float* be_g1 = (const float*)d_in[22];
    const float* g_g2 = (const float*)d_in[23]; const float* be_g2 = (const float*)d_in[24];
    const float* W_down = (const float*)d_in[25];
    const float* b_down = (const float*)d_in[26];

    char* ws = (char*)d_ws;
    const size_t MB = 1 << 20;
    int*   idx100 = (int*)  (ws + 0);                 // 1.64 MB
    float* st_l   = (float*)(ws + 0x1A0000);          // 6 stat blocks (a,b2)
    float* st_m0  = st_l + 256;
    float* st_m1  = st_l + 512;
    float* st_g0  = st_l + 768;
    float* st_g1  = st_l + 1024;
    float* st_g2  = st_l + 1280;
    float* nd100  = (float*)(ws +  2 * MB);           // 4.92 MB
    float* raw_l  = (float*)(ws +  8 * MB);           // 2 MB each
    float* raw_m0 = (float*)(ws + 10 * MB);
    float* raw_g0 = (float*)(ws + 12 * MB);
    float* raw_m1 = (float*)(ws + 14 * MB);
    float* raw_g1 = (float*)(ws + 16 * MB);
    float* raw_g2 = (float*)(ws + 18 * MB);
    float* fo_m   = (float*)(ws + 20 * MB);           // 4 MB each
    float* fo_g   = (float*)(ws + 24 * MB);
    float* fo_g2  = (float*)(ws + 28 * MB);

    // L1. KNN + neighbor directions
    knn_kernel<<<1024, 256, 0, stream>>>(verts, idx100, nd100);
    // L2. surface convs (k=5/20/100)
    surf3_kernel<<<4096, 128, 0, stream>>>(nd100, dirs_l, dirs_m0, dirs_g0,
                                           raw_l, raw_m0, raw_g0);
    // L3. BN stats for l, m0, g0
    fin_kernel<<<3, 1024, 0, stream>>>(raw_l, g_l, be_l, st_l,
                                       raw_m0, g_m0, be_m0, st_m0,
                                       raw_g0, g_g0, be_g0, st_g0);
    // L4. fo_m = bn_relu(raw_m0) @ W_m1 ; fo_g = bn_relu(raw_g0) @ W_g1
    gemm2_kernel<<<dim3(256, 2), 256, 0, stream>>>(raw_m0, st_m0, W_m1, b_m1, fo_m,
                                                   raw_g0, st_g0, W_g1, b_g1, fo_g);
    // L5. conv-layer apply (m1: K=20, g1: K=100)
    layer_kernel<<<dim3(4096, 2), 128, 0, stream>>>(nd100, idx100,
                                                    dirs_m1, fo_m, raw_m1, 20,
                                                    dirs_g1, fo_g, raw_g1, 100);
    // L6. BN stats for m1, g1
    fin_kernel<<<2, 1024, 0, stream>>>(raw_m1, g_m1, be_m1, st_m1,
                                       raw_g1, g_g1, be_g1, st_g1,
                                       raw_g1, g_g1, be_g1, st_g1);
    // L7. fo_g2 = bn_relu(raw_g1) @ W_g2
    gemm2_kernel<<<dim3(256, 1), 256, 0, stream>>>(raw_g1, st_g1, W_g2, b_g2, fo_g2,
                                                   raw_g1, st_g1, W_g2, b_g2, fo_g2);
    // L8. conv-layer apply (g2: K=100)
    layer_kernel<<<dim3(4096, 1), 128, 0, stream>>>(nd100, idx100,
                                                    dirs_g2, fo_g2, raw_g2, 100,
                                                    dirs_g2, fo_g2, raw_g2, 100);
    // L9. BN stats for g2
    fin_kernel<<<1, 1024, 0, stream>>>(raw_g2, g_g2, be_g2, st_g2,
                                       raw_g2, g_g2, be_g2, st_g2,
                                       raw_g2, g_g2, be_g2, st_g2);
    // L10. final: relu(concat(bn_relu each) @ W_down + b_down) -> fp32 out
    gemmf_kernel<<<256, 256, 0, stream>>>(raw_l, raw_m1, raw_g2,
                                          st_l, st_m1, st_g2,
                                          W_down, b_down, (float*)d_out);
}

// Round 8
// 312.997 us; speedup vs baseline: 1.7030x; 1.1908x over previous
//
#include <hip/hip_runtime.h>
#include <math.h>

typedef unsigned long long u64;

// ---------------------------------------------------------------------------
// Kernel 1: KNN, bit-exact vs the np/fp32 reference.
// Keys: (monotone fp32 dist << 10) | idx (unique). Bisect a threshold to
// ~101-320 candidates, compact to LDS, brute-force exact ranks, write
// ranks 1..100 (rank 0 dropped). One wave per row.
// ---------------------------------------------------------------------------
__global__ __launch_bounds__(256) void knn_kernel(const float* __restrict__ verts,
                                                  int* __restrict__ idx_out,
                                                  float* __restrict__ nd_out)
{
    __shared__ float vx[1024], vy[1024], vz[1024], sq[1024];
    __shared__ u64 cand[4][320];
    const int tid = threadIdx.x;
    const int row0 = blockIdx.x * 4;
    const int b = row0 >> 10;            // block never crosses a batch
    const float* vb = verts + b * 3072;

    for (int t = tid; t < 3072; t += 256) {
        float v = vb[t];
        int n = t / 3, c = t - n * 3;
        if (c == 0) vx[n] = v; else if (c == 1) vy[n] = v; else vz[n] = v;
    }
    __syncthreads();
    for (int n = tid; n < 1024; n += 256) {
        float x = vx[n], y = vy[n], z = vz[n];
        sq[n] = __fadd_rn(__fadd_rn(__fmul_rn(x, x), __fmul_rn(y, y)),
                          __fmul_rn(z, z));
    }
    __syncthreads();

    const int w = tid >> 6, lane = tid & 63;
    const int row = row0 + w;
    const int n_i = row & 1023;
    const float xi = vx[n_i], yi = vy[n_i], zi = vz[n_i];
    const float sqi = sq[n_i];

    u64 K[16];
#pragma unroll
    for (int t = 0; t < 16; ++t) {
        int j = t * 64 + lane;
        float dot = __fadd_rn(__fadd_rn(__fmul_rn(xi, vx[j]),
                                        __fmul_rn(yi, vy[j])),
                              __fmul_rn(zi, vz[j]));
        float d = __fsub_rn(__fadd_rn(sqi, sq[j]), __fmul_rn(2.0f, dot));
        d = __fadd_rn(d, 0.0f);          // canonicalize -0.0 -> +0.0
        unsigned u = __float_as_uint(d);
        unsigned m = (u & 0x80000000u) ? ~u : (u | 0x80000000u);
        K[t] = ((u64)m << 10) | (unsigned)j;
    }

    // 1) bisect threshold: count(key < hi) in [101, 320]
    u64 lo = 0, hi = 1ULL << 42;
    int chi = 1024;
    while (chi > 320) {
        u64 mid = (lo + hi) >> 1;
        int c = 0;
#pragma unroll
        for (int t = 0; t < 16; ++t) c += (K[t] < mid) ? 1 : 0;
#pragma unroll
        for (int off = 1; off < 64; off <<= 1) c += __shfl_xor(c, off);
        if (c >= 101) { hi = mid; chi = c; } else lo = mid;
    }
    const u64 T = hi;
    const int n = chi;                   // 101 <= n <= 320

    // 2) compact candidates < T via wave prefix-scan
    int myc_n = 0;
#pragma unroll
    for (int t = 0; t < 16; ++t) myc_n += (K[t] < T) ? 1 : 0;
    int sc = myc_n;
#pragma unroll
    for (int off = 1; off < 64; off <<= 1) {
        int v = __shfl_up(sc, off);
        if (lane >= off) sc += v;
    }
    int pos = sc - myc_n;
#pragma unroll
    for (int t = 0; t < 16; ++t) {
        if (K[t] < T) cand[w][pos++] = K[t];
    }
    __syncthreads();

    // 3) exact ranks within compacted set
    u64 myc[5]; int rk[5];
#pragma unroll
    for (int q = 0; q < 5; ++q) {
        int i = lane + q * 64;
        myc[q] = (i < n) ? cand[w][i] : ~0ULL;
        rk[q] = 0;
    }
    for (int jj = 0; jj < n; ++jj) {
        u64 kk = cand[w][jj];
#pragma unroll
        for (int q = 0; q < 5; ++q) rk[q] += (kk < myc[q]) ? 1 : 0;
    }

    // 4) write ranks 1..100
    const int rowbase = row & ~1023;
#pragma unroll
    for (int q = 0; q < 5; ++q) {
        int i = lane + q * 64;
        if (i < n) {
            int r = rk[q];
            if (r >= 1 && r <= 100) {
                int slot = r - 1;
                unsigned j = (unsigned)(myc[q] & 1023u);
                idx_out[row * 100 + slot] = rowbase + (int)j;
                float dx = vx[j] - xi, dy = vy[j] - yi, dz = vz[j] - zi;
                float nrm = sqrtf(__fadd_rn(__fadd_rn(__fmul_rn(dx, dx),
                                                      __fmul_rn(dy, dy)),
                                            __fmul_rn(dz, dz)));
                float inv = 1.0f / fmaxf(nrm, 1e-12f);
                float* o = nd_out + (row * 100 + slot) * 3;
                o[0] = dx * inv; o[1] = dy * inv; o[2] = dz * inv;
            }
        }
    }
}

// ---------------------------------------------------------------------------
// Kernel 2: fused surface conv, 3 scales (k=5/20/100 prefixes). One row per
// 128-thread block; nd reads wave-uniform -> scalar loads.
// ---------------------------------------------------------------------------
__global__ __launch_bounds__(128) void surf3_kernel(const float* __restrict__ nd,
    const float* __restrict__ dl, const float* __restrict__ dm, const float* __restrict__ dg,
    float* __restrict__ raw_l, float* __restrict__ raw_m, float* __restrict__ raw_g)
{
    const int d = threadIdx.x;
    const int row = blockIdx.x;

    float lx = dl[d], ly = dl[128 + d], lz = dl[256 + d];
    float li = 1.0f / fmaxf(sqrtf((lx * lx + ly * ly) + lz * lz), 1e-12f);
    lx *= li; ly *= li; lz *= li;
    float mx = dm[d], my = dm[128 + d], mz = dm[256 + d];
    float mi = 1.0f / fmaxf(sqrtf((mx * mx + my * my) + mz * mz), 1e-12f);
    mx *= mi; my *= mi; mz *= mi;
    float gx = dg[d], gy = dg[128 + d], gz = dg[256 + d];
    float gi = 1.0f / fmaxf(sqrtf((gx * gx + gy * gy) + gz * gz), 1e-12f);
    gx *= gi; gy *= gi; gz *= gi;

    const float* ns = nd + (size_t)row * 300;
    float ml = -1e30f, mm = -1e30f, mg = -1e30f;
    int k = 0;
    for (; k < 5; ++k) {
        float x = ns[3 * k], y = ns[3 * k + 1], z = ns[3 * k + 2];
        ml = fmaxf(ml, (x * lx + y * ly) + z * lz);
        mm = fmaxf(mm, (x * mx + y * my) + z * mz);
        mg = fmaxf(mg, (x * gx + y * gy) + z * gz);
    }
    for (; k < 20; ++k) {
        float x = ns[3 * k], y = ns[3 * k + 1], z = ns[3 * k + 2];
        mm = fmaxf(mm, (x * mx + y * my) + z * mz);
        mg = fmaxf(mg, (x * gx + y * gy) + z * gz);
    }
    for (; k < 100; ++k) {
        float x = ns[3 * k], y = ns[3 * k + 1], z = ns[3 * k + 2];
        mg = fmaxf(mg, (x * gx + y * gy) + z * gz);
    }
    raw_l[row * 128 + d] = fmaxf(ml, 0.0f);
    raw_m[row * 128 + d] = fmaxf(mm, 0.0f);
    raw_g[row * 128 + d] = fmaxf(mg, 0.0f);
}

// ---------------------------------------------------------------------------
// Kernel 3: BN partial sums: 8 blocks per tensor, each handles 512 rows,
// coalesced, fp64, deterministic (no atomics).
// Layout per tensor: p[blk*256 + c] = sum, p[blk*256 + 128 + c] = sumsq.
// ---------------------------------------------------------------------------
__global__ __launch_bounds__(256) void bnsum_kernel(
    const float* s0, double* p0,
    const float* s1, double* p1,
    const float* s2, double* p2)
{
    const int t = blockIdx.x >> 3;
    const int blk = blockIdx.x & 7;
    const float* src = (t == 0) ? s0 : (t == 1) ? s1 : s2;
    double* p = (t == 0) ? p0 : (t == 1) ? p1 : p2;
    const int tid = threadIdx.x;
    const int c = tid & 127, seg = tid >> 7;    // 2 segs x 256 rows
    const float* q = src + ((size_t)blk * 512 + seg * 256) * 128 + c;
    double s = 0.0, ss = 0.0;
    for (int r = 0; r < 256; ++r) { float v = q[r * 128]; s += v; ss += (double)v * v; }
    __shared__ double Ls[2][128], Lq[2][128];
    Ls[seg][c] = s; Lq[seg][c] = ss;
    __syncthreads();
    if (tid < 128) {
        p[blk * 256 + c]       = Ls[0][c] + Ls[1][c];
        p[blk * 256 + 128 + c] = Lq[0][c] + Lq[1][c];
    }
}

// st from partials: a = g/sqrt(var+eps), b2 = e - m*a (fp64, deterministic)
__device__ __forceinline__ void compute_st(const double* __restrict__ p,
                                           const float* __restrict__ g,
                                           const float* __restrict__ e,
                                           float* stA, float* stB,
                                           int tid, int nthreads)
{
    for (int c = tid; c < 128; c += nthreads) {
        double S = 0.0, Q = 0.0;
#pragma unroll
        for (int bb = 0; bb < 8; ++bb) { S += p[bb * 256 + c]; Q += p[bb * 256 + 128 + c]; }
        double m = S * (1.0 / 4096.0);
        double var = Q * (1.0 / 4096.0) - m * m;
        double a = (double)g[c] / sqrt(var + 1e-5);
        stA[c] = (float)a;
        stB[c] = (float)((double)e[c] - m * a);
    }
}

// ---------------------------------------------------------------------------
// Kernel 4: dual-job GEMM (CIN=128), 8 rows/block (grid 512 x 2 jobs).
// BN affine derived in-kernel from partials.
// ---------------------------------------------------------------------------
__global__ __launch_bounds__(256) void gemm2_kernel(
    const float* __restrict__ Aa, const double* __restrict__ pa,
    const float* __restrict__ ga, const float* __restrict__ ea,
    const float* __restrict__ Wa, const float* __restrict__ ba, float* __restrict__ outa,
    const float* __restrict__ Ab, const double* __restrict__ pb,
    const float* __restrict__ gb, const float* __restrict__ eb,
    const float* __restrict__ Wb, const float* __restrict__ bb, float* __restrict__ outb)
{
    const int job = blockIdx.y;
    const float* A = job ? Ab : Aa;  const double* p = job ? pb : pa;
    const float* g = job ? gb : ga;  const float* e = job ? eb : ea;
    const float* W = job ? Wb : Wa;  const float* bias = job ? bb : ba;
    float* out = job ? outb : outa;

    __shared__ float stA[128], stB[128];
    __shared__ float As[8 * 128];
    const int o = threadIdx.x;
    const int r0 = blockIdx.x * 8;

    compute_st(p, g, e, stA, stB, o, 256);
    __syncthreads();

    for (int t = o; t < 8 * 128; t += 256) {
        int r = t >> 7, c = t & 127;
        As[t] = fmaxf(fmaf(stA[c], A[(r0 + r) * 128 + c], stB[c]), 0.0f);
    }
    __syncthreads();

    float acc[8];
    const float bz = bias[o];
#pragma unroll
    for (int r = 0; r < 8; ++r) acc[r] = bz;

    for (int c = 0; c < 128; c += 4) {
        float w0 = W[(c + 0) * 256 + o];
        float w1 = W[(c + 1) * 256 + o];
        float w2 = W[(c + 2) * 256 + o];
        float w3 = W[(c + 3) * 256 + o];
#pragma unroll
        for (int r = 0; r < 8; ++r) {
            const float4 av = *(const float4*)&As[r * 128 + c];
            acc[r] += av.x * w0 + av.y * w1 + av.z * w2 + av.w * w3;
        }
    }
#pragma unroll
    for (int r = 0; r < 8; ++r)
        out[(r0 + r) * 256 + o] = acc[r];
}

// ---------------------------------------------------------------------------
// Kernel 5: conv-layer apply, 1 row per 128-thread block, up to 2 jobs via
// blockIdx.y. nd/idx reads wave-uniform -> scalar loads.
// ---------------------------------------------------------------------------
__global__ __launch_bounds__(128) void layer_kernel(
    const float* __restrict__ nd, const int* __restrict__ idxbuf,
    const float* dir0, const float* fo0, float* out0, int K0,
    const float* dir1, const float* fo1, float* out1, int K1)
{
    const int job = blockIdx.y;
    const float* dirs = job ? dir1 : dir0;
    const float* fo = job ? fo1 : fo0;
    float* out = job ? out1 : out0;
    const int K = job ? K1 : K0;

    const int d = threadIdx.x;
    const int row = blockIdx.x;

    float dx = dirs[d], dy = dirs[128 + d], dz = dirs[256 + d];
    float di = 1.0f / fmaxf(sqrtf((dx * dx + dy * dy) + dz * dz), 1e-12f);
    dx *= di; dy *= di; dz *= di;

    const float* ns = nd + (size_t)row * 300;
    const int* ib = idxbuf + (size_t)row * 100;

    float acc = -1e30f;
    for (int k = 0; k < K; ++k) {
        float x = ns[3 * k], y = ns[3 * k + 1], z = ns[3 * k + 2];
        int ix = ib[k];
        float th = fmaxf((x * dx + y * dy) + z * dz, 0.0f);
        float fs = fo[ix * 256 + 128 + d];
        acc = fmaxf(acc, th * fs);
    }
    out[row * 128 + d] = fo[row * 256 + d] + acc;
}

// ---------------------------------------------------------------------------
// Kernel 6: final GEMM (CIN=384), 8 rows/block (grid 512), BN affines for
// 3 segments derived in-kernel, final relu, fp32 out.
// ---------------------------------------------------------------------------
__global__ __launch_bounds__(256) void gemmf_kernel(
    const float* __restrict__ A0, const double* __restrict__ p0,
    const float* __restrict__ g0, const float* __restrict__ e0,
    const float* __restrict__ A1, const double* __restrict__ p1,
    const float* __restrict__ g1, const float* __restrict__ e1,
    const float* __restrict__ A2, const double* __restrict__ p2,
    const float* __restrict__ g2, const float* __restrict__ e2,
    const float* __restrict__ W, const float* __restrict__ bias, float* __restrict__ out)
{
    __shared__ float stA[384], stB[384];
    __shared__ float As[8 * 384];
    const int o = threadIdx.x;
    const int r0 = blockIdx.x * 8;

    compute_st(p0, g0, e0, stA,       stB,       o, 256);
    compute_st(p1, g1, e1, stA + 128, stB + 128, o, 256);
    compute_st(p2, g2, e2, stA + 256, stB + 256, o, 256);
    __syncthreads();

    for (int t = o; t < 8 * 384; t += 256) {
        int r = t / 384, c = t - r * 384;
        int seg = c >> 7, cc = c & 127;
        const float* A = (seg == 0) ? A0 : (seg == 1) ? A1 : A2;
        As[t] = fmaxf(fmaf(stA[c], A[(r0 + r) * 128 + cc], stB[c]), 0.0f);
    }
    __syncthreads();

    float acc[8];
    const float bz = bias[o];
#pragma unroll
    for (int r = 0; r < 8; ++r) acc[r] = bz;

    for (int c = 0; c < 384; c += 4) {
        float w0 = W[(c + 0) * 256 + o];
        float w1 = W[(c + 1) * 256 + o];
        float w2 = W[(c + 2) * 256 + o];
        float w3 = W[(c + 3) * 256 + o];
#pragma unroll
        for (int r = 0; r < 8; ++r) {
            const float4 av = *(const float4*)&As[r * 384 + c];
            acc[r] += av.x * w0 + av.y * w1 + av.z * w2 + av.w * w3;
        }
    }
#pragma unroll
    for (int r = 0; r < 8; ++r)
        out[(r0 + r) * 256 + o] = fmaxf(acc[r], 0.0f);
}

// ---------------------------------------------------------------------------
extern "C" void kernel_launch(void* const* d_in, const int* in_sizes, int n_in,
                              void* d_out, int out_size, void* d_ws, size_t ws_size,
                              hipStream_t stream)
{
    (void)in_sizes; (void)n_in; (void)out_size; (void)ws_size;

    const float* verts   = (const float*)d_in[0];
    const float* dirs_l  = (const float*)d_in[1];
    const float* dirs_m0 = (const float*)d_in[2];
    const float* W_m1    = (const float*)d_in[3];
    const float* b_m1    = (const float*)d_in[4];
    const float* dirs_m1 = (const float*)d_in[5];
    const float* dirs_g0 = (const float*)d_in[6];
    const float* W_g1    = (const float*)d_in[7];
    const float* b_g1    = (const float*)d_in[8];
    const float* dirs_g1 = (const float*)d_in[9];
    const float* W_g2    = (const float*)d_in[10];
    const float* b_g2    = (const float*)d_in[11];
    const float* dirs_g2 = (const float*)d_in[12];
    const float* g_l  = (const float*)d_in[13]; const float* be_l  = (const float*)d_in[14];
    const float* g_m0 = (const float*)d_in[15]; const float* be_m0 = (const float*)d_in[16];
    const float* g_m1 = (const float*)d_in[17]; const float* be_m1 = (const float*)d_in[18];
    const float* g_g0 = (const float*)d_in[19]; const float* be_g0 = (const float*)d_in[20];
    const float* g_g1 = (const float*)d_in[21]; const float* be_g1 = (const float*)d_in[22];
    const float* g_g2 = (const float*)d_in[23]; const float* be_g2 = (const float*)d_in[24];
    const float* W_down = (const float*)d_in[25];
    const float* b_down = (const float*)d_in[26];

    char* ws = (char*)d_ws;
    const size_t MB = 1 << 20;
    int*    idx100 = (int*)   (ws + 0);               // 1.64 MB
    double* p_l    = (double*)(ws + 0x1A0000);        // 6 x 16 KB fp64 partials
    double* p_m0   = p_l  + 2048;
    double* p_m1   = p_m0 + 2048;
    double* p_g0   = p_m1 + 2048;
    double* p_g1   = p_g0 + 2048;
    double* p_g2   = p_g1 + 2048;
    float* nd100  = (float*)(ws +  2 * MB);           // 4.92 MB
    float* raw_l  = (float*)(ws +  8 * MB);           // 2 MB each
    float* raw_m0 = (float*)(ws + 10 * MB);
    float* raw_g0 = (float*)(ws + 12 * MB);
    float* raw_m1 = (float*)(ws + 14 * MB);
    float* raw_g1 = (float*)(ws + 16 * MB);
    float* raw_g2 = (float*)(ws + 18 * MB);
    float* fo_m   = (float*)(ws + 20 * MB);           // 4 MB each
    float* fo_g   = (float*)(ws + 24 * MB);
    float* fo_g2  = (float*)(ws + 28 * MB);

    // L1. KNN + neighbor directions
    knn_kernel<<<1024, 256, 0, stream>>>(verts, idx100, nd100);
    // L2. surface convs (k=5/20/100)
    surf3_kernel<<<4096, 128, 0, stream>>>(nd100, dirs_l, dirs_m0, dirs_g0,
                                           raw_l, raw_m0, raw_g0);
    // L3. BN partials for l, m0, g0
    bnsum_kernel<<<24, 256, 0, stream>>>(raw_l, p_l, raw_m0, p_m0, raw_g0, p_g0);
    // L4. fo_m = bn_relu(raw_m0) @ W_m1 ; fo_g = bn_relu(raw_g0) @ W_g1
    gemm2_kernel<<<dim3(512, 2), 256, 0, stream>>>(
        raw_m0, p_m0, g_m0, be_m0, W_m1, b_m1, fo_m,
        raw_g0, p_g0, g_g0, be_g0, W_g1, b_g1, fo_g);
    // L5. conv-layer apply (m1: K=20, g1: K=100)
    layer_kernel<<<dim3(4096, 2), 128, 0, stream>>>(nd100, idx100,
                                                    dirs_m1, fo_m, raw_m1, 20,
                                                    dirs_g1, fo_g, raw_g1, 100);
    // L6. BN partials for m1, g1
    bnsum_kernel<<<16, 256, 0, stream>>>(raw_m1, p_m1, raw_g1, p_g1, raw_g1, p_g1);
    // L7. fo_g2 = bn_relu(raw_g1) @ W_g2
    gemm2_kernel<<<dim3(512, 1), 256, 0, stream>>>(
        raw_g1, p_g1, g_g1, be_g1, W_g2, b_g2, fo_g2,
        raw_g1, p_g1, g_g1, be_g1, W_g2, b_g2, fo_g2);
    // L8. conv-layer apply (g2: K=100)
    layer_kernel<<<dim3(4096, 1), 128, 0, stream>>>(nd100, idx100,
                                                    dirs_g2, fo_g2, raw_g2, 100,
                                                    dirs_g2, fo_g2, raw_g2, 100);
    // L9. BN partials for g2
    bnsum_kernel<<<8, 256, 0, stream>>>(raw_g2, p_g2, raw_g2, p_g2, raw_g2, p_g2);
    // L10. final: relu(concat(bn_relu each) @ W_down + b_down) -> fp32 out
    gemmf_kernel<<<512, 256, 0, stream>>>(raw_l, p_l, g_l, be_l,
                                          raw_m1, p_m1, g_m1, be_m1,
                                          raw_g2, p_g2, g_g2, be_g2,
                                          W_down, b_down, (float*)d_out);
}

// Round 9
// 288.961 us; speedup vs baseline: 1.8447x; 1.0832x over previous
//
#include <hip/hip_runtime.h>
#include <math.h>

typedef unsigned long long u64;

// ---------------------------------------------------------------------------
// Kernel 1: KNN (bit-exact vs np/fp32 reference) + fused 3-scale surface conv.
// Keys: (monotone fp32 dist << 10) | idx (unique).
//  1) threshold T = wave-max of per-lane 2nd-smallest key (count>=127);
//     bisect [wave-min, T] only if count > 320 (rare).
//  2) compact candidates < T to LDS via wave prefix-scan
//  3) brute-force exact ranks; rank 0 dropped, ranks 1..100 -> slots 0..99
//  4) nd written to global AND to LDS by rank; then the block computes
//     surf_l/m/g (k=5/20/100 prefixes) for its 4 rows from LDS.
// One wave per row, 4 rows per 256-thread block.
// ---------------------------------------------------------------------------
__global__ __launch_bounds__(256) void knnsurf_kernel(
    const float* __restrict__ verts,
    int* __restrict__ idx_out, float* __restrict__ nd_out,
    const float* __restrict__ dl, const float* __restrict__ dm,
    const float* __restrict__ dg,
    float* __restrict__ raw_l, float* __restrict__ raw_m, float* __restrict__ raw_g)
{
    __shared__ float vx[1024], vy[1024], vz[1024], sq[1024];
    __shared__ u64 cand[4][320];
    float* ndsh = (float*)&cand[0][0];   // row rr: floats [rr*640 .. rr*640+299]
    const int tid = threadIdx.x;
    const int row0 = blockIdx.x * 4;
    const int b = row0 >> 10;            // block never crosses a batch
    const float* vb = verts + b * 3072;

    for (int t = tid; t < 3072; t += 256) {
        float v = vb[t];
        int n = t / 3, c = t - n * 3;
        if (c == 0) vx[n] = v; else if (c == 1) vy[n] = v; else vz[n] = v;
    }
    __syncthreads();
    for (int n = tid; n < 1024; n += 256) {
        float x = vx[n], y = vy[n], z = vz[n];
        sq[n] = __fadd_rn(__fadd_rn(__fmul_rn(x, x), __fmul_rn(y, y)),
                          __fmul_rn(z, z));
    }
    __syncthreads();

    const int w = tid >> 6, lane = tid & 63;
    const int row = row0 + w;
    const int n_i = row & 1023;
    const float xi = vx[n_i], yi = vy[n_i], zi = vz[n_i];
    const float sqi = sq[n_i];

    u64 K[16];
    u64 m1 = ~0ULL, m2 = ~0ULL;          // per-lane two smallest
#pragma unroll
    for (int t = 0; t < 16; ++t) {
        int j = t * 64 + lane;
        float dot = __fadd_rn(__fadd_rn(__fmul_rn(xi, vx[j]),
                                        __fmul_rn(yi, vy[j])),
                              __fmul_rn(zi, vz[j]));
        float d = __fsub_rn(__fadd_rn(sqi, sq[j]), __fmul_rn(2.0f, dot));
        d = __fadd_rn(d, 0.0f);          // canonicalize -0.0 -> +0.0
        unsigned u = __float_as_uint(d);
        unsigned m = (u & 0x80000000u) ? ~u : (u | 0x80000000u);
        u64 k = ((u64)m << 10) | (unsigned)j;
        K[t] = k;
        bool lt1 = k < m1;
        u64 nm2 = lt1 ? m1 : ((k < m2) ? k : m2);
        m1 = lt1 ? k : m1;
        m2 = nm2;
    }

    // wave-max(m2) and wave-min(m1)
    u64 tmax = m2, tmin = m1;
#pragma unroll
    for (int off = 1; off < 64; off <<= 1) {
        u64 a = __shfl_xor(tmax, off); if (a > tmax) tmax = a;
        u64 c = __shfl_xor(tmin, off); if (c < tmin) tmin = c;
    }

    // count at T = tmax (guaranteed >= 127)
    u64 T = tmax;
    int chi;
    {
        int c = 0;
#pragma unroll
        for (int t = 0; t < 16; ++t) c += (K[t] < T) ? 1 : 0;
#pragma unroll
        for (int off = 1; off < 64; off <<= 1) c += __shfl_xor(c, off);
        chi = c;
    }
    // rare fallback: bisect tight range [tmin, T]
    u64 lo = tmin, hi = T;
    while (chi > 320) {
        u64 mid = (lo + hi) >> 1;
        int c = 0;
#pragma unroll
        for (int t = 0; t < 16; ++t) c += (K[t] < mid) ? 1 : 0;
#pragma unroll
        for (int off = 1; off < 64; off <<= 1) c += __shfl_xor(c, off);
        if (c >= 101) { hi = mid; chi = c; } else lo = mid;
    }
    T = hi;
    const int n = chi;                   // 101 <= n <= 320

    // compact candidates < T via wave prefix-scan
    int myc_n = 0;
#pragma unroll
    for (int t = 0; t < 16; ++t) myc_n += (K[t] < T) ? 1 : 0;
    int sc = myc_n;
#pragma unroll
    for (int off = 1; off < 64; off <<= 1) {
        int v = __shfl_up(sc, off);
        if (lane >= off) sc += v;
    }
    int pos = sc - myc_n;
#pragma unroll
    for (int t = 0; t < 16; ++t) {
        if (K[t] < T) cand[w][pos++] = K[t];
    }
    __syncthreads();

    // exact ranks within compacted set
    u64 myc[5]; int rk[5];
#pragma unroll
    for (int q = 0; q < 5; ++q) {
        int i = lane + q * 64;
        myc[q] = (i < n) ? cand[w][i] : ~0ULL;
        rk[q] = 0;
    }
    for (int jj = 0; jj < n; ++jj) {
        u64 kk = cand[w][jj];
#pragma unroll
        for (int q = 0; q < 5; ++q) rk[q] += (kk < myc[q]) ? 1 : 0;
    }

    // write ranks 1..100 to global AND to LDS (ndsh aliases cand[w] -
    // wave-private region, program order within the wave makes it safe)
    const int rowbase = row & ~1023;
    float* nds_w = ndsh + w * 640;
#pragma unroll
    for (int q = 0; q < 5; ++q) {
        int i = lane + q * 64;
        if (i < n) {
            int r = rk[q];
            if (r >= 1 && r <= 100) {
                int slot = r - 1;
                unsigned j = (unsigned)(myc[q] & 1023u);
                idx_out[row * 100 + slot] = rowbase + (int)j;
                float dx = vx[j] - xi, dy = vy[j] - yi, dz = vz[j] - zi;
                float nrm = sqrtf(__fadd_rn(__fadd_rn(__fmul_rn(dx, dx),
                                                      __fmul_rn(dy, dy)),
                                            __fmul_rn(dz, dz)));
                float inv = 1.0f / fmaxf(nrm, 1e-12f);
                float* o = nd_out + (row * 100 + slot) * 3;
                float nx = dx * inv, ny = dy * inv, nz = dz * inv;
                o[0] = nx; o[1] = ny; o[2] = nz;
                nds_w[3 * slot] = nx; nds_w[3 * slot + 1] = ny; nds_w[3 * slot + 2] = nz;
            }
        }
    }
    __syncthreads();

    // ---- fused surface conv for the block's 4 rows ----
    const int d = tid & 127;
    float lx = dl[d], ly = dl[128 + d], lz = dl[256 + d];
    float li = 1.0f / fmaxf(sqrtf((lx * lx + ly * ly) + lz * lz), 1e-12f);
    lx *= li; ly *= li; lz *= li;
    float mx = dm[d], my = dm[128 + d], mz = dm[256 + d];
    float mi = 1.0f / fmaxf(sqrtf((mx * mx + my * my) + mz * mz), 1e-12f);
    mx *= mi; my *= mi; mz *= mi;
    float gx = dg[d], gy = dg[128 + d], gz = dg[256 + d];
    float gi = 1.0f / fmaxf(sqrtf((gx * gx + gy * gy) + gz * gz), 1e-12f);
    gx *= gi; gy *= gi; gz *= gi;

#pragma unroll
    for (int p = 0; p < 2; ++p) {
        int rr = (tid >> 7) + 2 * p;     // wave-uniform
        const float* ns = ndsh + rr * 640;
        float ml = -1e30f, mm = -1e30f, mg = -1e30f;
        int k = 0;
        for (; k < 5; ++k) {
            float x = ns[3 * k], y = ns[3 * k + 1], z = ns[3 * k + 2];
            ml = fmaxf(ml, (x * lx + y * ly) + z * lz);
            mm = fmaxf(mm, (x * mx + y * my) + z * mz);
            mg = fmaxf(mg, (x * gx + y * gy) + z * gz);
        }
        for (; k < 20; ++k) {
            float x = ns[3 * k], y = ns[3 * k + 1], z = ns[3 * k + 2];
            mm = fmaxf(mm, (x * mx + y * my) + z * mz);
            mg = fmaxf(mg, (x * gx + y * gy) + z * gz);
        }
        for (; k < 100; ++k) {
            float x = ns[3 * k], y = ns[3 * k + 1], z = ns[3 * k + 2];
            mg = fmaxf(mg, (x * gx + y * gy) + z * gz);
        }
        int orow = row0 + rr;
        raw_l[orow * 128 + d] = fmaxf(ml, 0.0f);
        raw_m[orow * 128 + d] = fmaxf(mm, 0.0f);
        raw_g[orow * 128 + d] = fmaxf(mg, 0.0f);
    }
}

// ---------------------------------------------------------------------------
// Kernel 2: BN partial sums: 32 blocks per tensor, 128 rows each, coalesced,
// fp64, deterministic. Layout: p[blk*256+c]=sum, p[blk*256+128+c]=sumsq.
// ---------------------------------------------------------------------------
__global__ __launch_bounds__(256) void bnsum_kernel(
    const float* s0, double* p0,
    const float* s1, double* p1,
    const float* s2, double* p2)
{
    const int t = blockIdx.x >> 5;
    const int blk = blockIdx.x & 31;
    const float* src = (t == 0) ? s0 : (t == 1) ? s1 : s2;
    double* p = (t == 0) ? p0 : (t == 1) ? p1 : p2;
    const int tid = threadIdx.x;
    const int c = tid & 127, seg = tid >> 7;    // 2 segs x 64 rows
    const float* q = src + ((size_t)blk * 128 + seg * 64) * 128 + c;
    double s = 0.0, ss = 0.0;
    for (int r = 0; r < 64; ++r) { float v = q[r * 128]; s += v; ss += (double)v * v; }
    __shared__ double Ls[2][128], Lq[2][128];
    Ls[seg][c] = s; Lq[seg][c] = ss;
    __syncthreads();
    if (tid < 128) {
        p[blk * 256 + c]       = Ls[0][c] + Ls[1][c];
        p[blk * 256 + 128 + c] = Lq[0][c] + Lq[1][c];
    }
}

// st from partials: a = g/sqrt(var+eps), b2 = e - m*a (fp64, deterministic)
__device__ __forceinline__ void compute_st(const double* __restrict__ p,
                                           const float* __restrict__ g,
                                           const float* __restrict__ e,
                                           float* stA, float* stB,
                                           int tid, int nthreads)
{
    for (int c = tid; c < 128; c += nthreads) {
        double S = 0.0, Q = 0.0;
#pragma unroll
        for (int bb = 0; bb < 32; ++bb) { S += p[bb * 256 + c]; Q += p[bb * 256 + 128 + c]; }
        double m = S * (1.0 / 4096.0);
        double var = Q * (1.0 / 4096.0) - m * m;
        double a = (double)g[c] / sqrt(var + 1e-5);
        stA[c] = (float)a;
        stB[c] = (float)((double)e[c] - m * a);
    }
}

// ---------------------------------------------------------------------------
// Kernel 3: dual-job GEMM (CIN=128), 8 rows/block (grid 512 x jobs).
// BN affine derived in-kernel from partials.
// ---------------------------------------------------------------------------
__global__ __launch_bounds__(256) void gemm2_kernel(
    const float* __restrict__ Aa, const double* __restrict__ pa,
    const float* __restrict__ ga, const float* __restrict__ ea,
    const float* __restrict__ Wa, const float* __restrict__ ba, float* __restrict__ outa,
    const float* __restrict__ Ab, const double* __restrict__ pb,
    const float* __restrict__ gb, const float* __restrict__ eb,
    const float* __restrict__ Wb, const float* __restrict__ bb, float* __restrict__ outb)
{
    const int job = blockIdx.y;
    const float* A = job ? Ab : Aa;  const double* p = job ? pb : pa;
    const float* g = job ? gb : ga;  const float* e = job ? eb : ea;
    const float* W = job ? Wb : Wa;  const float* bias = job ? bb : ba;
    float* out = job ? outb : outa;

    __shared__ float stA[128], stB[128];
    __shared__ float As[8 * 128];
    const int o = threadIdx.x;
    const int r0 = blockIdx.x * 8;

    compute_st(p, g, e, stA, stB, o, 256);
    __syncthreads();

    for (int t = o; t < 8 * 128; t += 256) {
        int r = t >> 7, c = t & 127;
        As[t] = fmaxf(fmaf(stA[c], A[(r0 + r) * 128 + c], stB[c]), 0.0f);
    }
    __syncthreads();

    float acc[8];
    const float bz = bias[o];
#pragma unroll
    for (int r = 0; r < 8; ++r) acc[r] = bz;

    for (int c = 0; c < 128; c += 4) {
        float w0 = W[(c + 0) * 256 + o];
        float w1 = W[(c + 1) * 256 + o];
        float w2 = W[(c + 2) * 256 + o];
        float w3 = W[(c + 3) * 256 + o];
#pragma unroll
        for (int r = 0; r < 8; ++r) {
            const float4 av = *(const float4*)&As[r * 128 + c];
            acc[r] += av.x * w0 + av.y * w1 + av.z * w2 + av.w * w3;
        }
    }
#pragma unroll
    for (int r = 0; r < 8; ++r)
        out[(r0 + r) * 256 + o] = acc[r];
}

// ---------------------------------------------------------------------------
// Kernel 4: conv-layer apply, 1 row per 128-thread block, up to 2 jobs via
// blockIdx.y. nd/idx reads wave-uniform -> scalar loads.
// ---------------------------------------------------------------------------
__global__ __launch_bounds__(128) void layer_kernel(
    const float* __restrict__ nd, const int* __restrict__ idxbuf,
    const float* dir0, const float* fo0, float* out0, int K0,
    const float* dir1, const float* fo1, float* out1, int K1)
{
    const int job = blockIdx.y;
    const float* dirs = job ? dir1 : dir0;
    const float* fo = job ? fo1 : fo0;
    float* out = job ? out1 : out0;
    const int K = job ? K1 : K0;

    const int d = threadIdx.x;
    const int row = blockIdx.x;

    float dx = dirs[d], dy = dirs[128 + d], dz = dirs[256 + d];
    float di = 1.0f / fmaxf(sqrtf((dx * dx + dy * dy) + dz * dz), 1e-12f);
    dx *= di; dy *= di; dz *= di;

    const float* ns = nd + (size_t)row * 300;
    const int* ib = idxbuf + (size_t)row * 100;

    float acc = -1e30f;
    for (int k = 0; k < K; ++k) {
        float x = ns[3 * k], y = ns[3 * k + 1], z = ns[3 * k + 2];
        int ix = ib[k];
        float th = fmaxf((x * dx + y * dy) + z * dz, 0.0f);
        float fs = fo[ix * 256 + 128 + d];
        acc = fmaxf(acc, th * fs);
    }
    out[row * 128 + d] = fo[row * 256 + d] + acc;
}

// ---------------------------------------------------------------------------
// Kernel 5: final GEMM (CIN=384), 8 rows/block (grid 512), BN affines for
// 3 segments derived in-kernel, final relu, fp32 out.
// ---------------------------------------------------------------------------
__global__ __launch_bounds__(256) void gemmf_kernel(
    const float* __restrict__ A0, const double* __restrict__ p0,
    const float* __restrict__ g0, const float* __restrict__ e0,
    const float* __restrict__ A1, const double* __restrict__ p1,
    const float* __restrict__ g1, const float* __restrict__ e1,
    const float* __restrict__ A2, const double* __restrict__ p2,
    const float* __restrict__ g2, const float* __restrict__ e2,
    const float* __restrict__ W, const float* __restrict__ bias, float* __restrict__ out)
{
    __shared__ float stA[384], stB[384];
    __shared__ float As[8 * 384];
    const int o = threadIdx.x;
    const int r0 = blockIdx.x * 8;

    compute_st(p0, g0, e0, stA,       stB,       o, 256);
    compute_st(p1, g1, e1, stA + 128, stB + 128, o, 256);
    compute_st(p2, g2, e2, stA + 256, stB + 256, o, 256);
    __syncthreads();

    for (int t = o; t < 8 * 384; t += 256) {
        int r = t / 384, c = t - r * 384;
        int seg = c >> 7, cc = c & 127;
        const float* A = (seg == 0) ? A0 : (seg == 1) ? A1 : A2;
        As[t] = fmaxf(fmaf(stA[c], A[(r0 + r) * 128 + cc], stB[c]), 0.0f);
    }
    __syncthreads();

    float acc[8];
    const float bz = bias[o];
#pragma unroll
    for (int r = 0; r < 8; ++r) acc[r] = bz;

    for (int c = 0; c < 384; c += 4) {
        float w0 = W[(c + 0) * 256 + o];
        float w1 = W[(c + 1) * 256 + o];
        float w2 = W[(c + 2) * 256 + o];
        float w3 = W[(c + 3) * 256 + o];
#pragma unroll
        for (int r = 0; r < 8; ++r) {
            const float4 av = *(const float4*)&As[r * 384 + c];
            acc[r] += av.x * w0 + av.y * w1 + av.z * w2 + av.w * w3;
        }
    }
#pragma unroll
    for (int r = 0; r < 8; ++r)
        out[(r0 + r) * 256 + o] = fmaxf(acc[r], 0.0f);
}

// ---------------------------------------------------------------------------
extern "C" void kernel_launch(void* const* d_in, const int* in_sizes, int n_in,
                              void* d_out, int out_size, void* d_ws, size_t ws_size,
                              hipStream_t stream)
{
    (void)in_sizes; (void)n_in; (void)out_size; (void)ws_size;

    const float* verts   = (const float*)d_in[0];
    const float* dirs_l  = (const float*)d_in[1];
    const float* dirs_m0 = (const float*)d_in[2];
    const float* W_m1    = (const float*)d_in[3];
    const float* b_m1    = (const float*)d_in[4];
    const float* dirs_m1 = (const float*)d_in[5];
    const float* dirs_g0 = (const float*)d_in[6];
    const float* W_g1    = (const float*)d_in[7];
    const float* b_g1    = (const float*)d_in[8];
    const float* dirs_g1 = (const float*)d_in[9];
    const float* W_g2    = (const float*)d_in[10];
    const float* b_g2    = (const float*)d_in[11];
    const float* dirs_g2 = (const float*)d_in[12];
    const float* g_l  = (const float*)d_in[13]; const float* be_l  = (const float*)d_in[14];
    const float* g_m0 = (const float*)d_in[15]; const float* be_m0 = (const float*)d_in[16];
    const float* g_m1 = (const float*)d_in[17]; const float* be_m1 = (const float*)d_in[18];
    const float* g_g0 = (const float*)d_in[19]; const float* be_g0 = (const float*)d_in[20];
    const float* g_g1 = (const float*)d_in[21]; const float* be_g1 = (const float*)d_in[22];
    const float* g_g2 = (const float*)d_in[23]; const float* be_g2 = (const float*)d_in[24];
    const float* W_down = (const float*)d_in[25];
    const float* b_down = (const float*)d_in[26];

    char* ws = (char*)d_ws;
    const size_t MB = 1 << 20;
    int*    idx100 = (int*)   (ws + 0);               // 1.64 MB
    double* p_l    = (double*)(ws + 0x1A0000);        // 6 x 64 KB fp64 partials
    double* p_m0   = p_l  + 8192;
    double* p_m1   = p_m0 + 8192;
    double* p_g0   = p_m1 + 8192;
    double* p_g1   = p_g0 + 8192;
    double* p_g2   = p_g1 + 8192;
    float* nd100  = (float*)(ws +  2 * MB);           // 4.92 MB
    float* raw_l  = (float*)(ws +  8 * MB);           // 2 MB each
    float* raw_m0 = (float*)(ws + 10 * MB);
    float* raw_g0 = (float*)(ws + 12 * MB);
    float* raw_m1 = (float*)(ws + 14 * MB);
    float* raw_g1 = (float*)(ws + 16 * MB);
    float* raw_g2 = (float*)(ws + 18 * MB);
    float* fo_m   = (float*)(ws + 20 * MB);           // 4 MB each
    float* fo_g   = (float*)(ws + 24 * MB);
    float* fo_g2  = (float*)(ws + 28 * MB);

    // L1. KNN + nd + fused surface convs (k=5/20/100)
    knnsurf_kernel<<<1024, 256, 0, stream>>>(verts, idx100, nd100,
                                             dirs_l, dirs_m0, dirs_g0,
                                             raw_l, raw_m0, raw_g0);
    // L2. BN partials for l, m0, g0
    bnsum_kernel<<<96, 256, 0, stream>>>(raw_l, p_l, raw_m0, p_m0, raw_g0, p_g0);
    // L3. fo_m = bn_relu(raw_m0) @ W_m1 ; fo_g = bn_relu(raw_g0) @ W_g1
    gemm2_kernel<<<dim3(512, 2), 256, 0, stream>>>(
        raw_m0, p_m0, g_m0, be_m0, W_m1, b_m1, fo_m,
        raw_g0, p_g0, g_g0, be_g0, W_g1, b_g1, fo_g);
    // L4. conv-layer apply (m1: K=20, g1: K=100)
    layer_kernel<<<dim3(4096, 2), 128, 0, stream>>>(nd100, idx100,
                                                    dirs_m1, fo_m, raw_m1, 20,
                                                    dirs_g1, fo_g, raw_g1, 100);
    // L5. BN partials for m1, g1
    bnsum_kernel<<<64, 256, 0, stream>>>(raw_m1, p_m1, raw_g1, p_g1, raw_g1, p_g1);
    // L6. fo_g2 = bn_relu(raw_g1) @ W_g2
    gemm2_kernel<<<dim3(512, 1), 256, 0, stream>>>(
        raw_g1, p_g1, g_g1, be_g1, W_g2, b_g2, fo_g2,
        raw_g1, p_g1, g_g1, be_g1, W_g2, b_g2, fo_g2);
    // L7. conv-layer apply (g2: K=100)
    layer_kernel<<<dim3(4096, 1), 128, 0, stream>>>(nd100, idx100,
                                                    dirs_g2, fo_g2, raw_g2, 100,
                                                    dirs_g2, fo_g2, raw_g2, 100);
    // L8. BN partials for g2
    bnsum_kernel<<<32, 256, 0, stream>>>(raw_g2, p_g2, raw_g2, p_g2, raw_g2, p_g2);
    // L9. final: relu(concat(bn_relu each) @ W_down + b_down) -> fp32 out
    gemmf_kernel<<<512, 256, 0, stream>>>(raw_l, p_l, g_l, be_l,
                                          raw_m1, p_m1, g_m1, be_m1,
                                          raw_g2, p_g2, g_g2, be_g2,
                                          W_down, b_down, (float*)d_out);
}

// Round 10
// 273.764 us; speedup vs baseline: 1.9471x; 1.0555x over previous
//
#include <hip/hip_runtime.h>
#include <math.h>

typedef unsigned long long u64;

// ---------------------------------------------------------------------------
// Kernel 1: KNN (bit-exact vs np/fp32 reference) + fused 3-scale surface conv.
// Keys: (monotone fp32 dist << 10) | idx (unique).
//  1) seed threshold T = wave-max of per-lane 2nd-smallest key (count>=127);
//     bisect tight range down to count <= 192.
//  2) compact candidates < T to LDS via wave prefix-scan
//  3) brute-force exact ranks (pairs via b128); rank 0 dropped,
//     ranks 1..100 -> slots 0..99
//  4) nd written (float4) to global AND LDS by rank; block then computes
//     surf_l/m/g (k=5/20/100 prefixes) for its 4 rows from LDS.
// One wave per row, 4 rows per 256-thread block. LDS ~22.7 KB.
// ---------------------------------------------------------------------------
__global__ __launch_bounds__(256) void knnsurf_kernel(
    const float* __restrict__ verts,
    int* __restrict__ idx_out, float4* __restrict__ nd_out,
    const float* __restrict__ dl, const float* __restrict__ dm,
    const float* __restrict__ dg,
    float* __restrict__ raw_l, float* __restrict__ raw_m, float* __restrict__ raw_g)
{
    __shared__ float4 vps[1024];                    // x,y,z,sq  (16 KB)
    __shared__ __align__(16) u64 cand[4][208];      // 6.7 KB; row = 16B-aligned
    const int tid = threadIdx.x;
    const int row0 = blockIdx.x * 4;
    const int b = row0 >> 10;            // block never crosses a batch
    const float* vb = verts + b * 3072;

    for (int n = tid; n < 1024; n += 256) {
        float x = vb[3 * n], y = vb[3 * n + 1], z = vb[3 * n + 2];
        float s = __fadd_rn(__fadd_rn(__fmul_rn(x, x), __fmul_rn(y, y)),
                            __fmul_rn(z, z));
        vps[n] = make_float4(x, y, z, s);
    }
    __syncthreads();

    const int w = tid >> 6, lane = tid & 63;
    const int row = row0 + w;
    const int n_i = row & 1023;
    const float4 pi = vps[n_i];
    const float xi = pi.x, yi = pi.y, zi = pi.z, sqi = pi.w;

    u64 K[16];
    u64 m1 = ~0ULL, m2 = ~0ULL;          // per-lane two smallest
#pragma unroll
    for (int t = 0; t < 16; ++t) {
        int j = t * 64 + lane;
        float4 p = vps[j];
        float dot = __fadd_rn(__fadd_rn(__fmul_rn(xi, p.x),
                                        __fmul_rn(yi, p.y)),
                              __fmul_rn(zi, p.z));
        float d = __fsub_rn(__fadd_rn(sqi, p.w), __fmul_rn(2.0f, dot));
        d = __fadd_rn(d, 0.0f);          // canonicalize -0.0 -> +0.0
        unsigned u = __float_as_uint(d);
        unsigned m = (u & 0x80000000u) ? ~u : (u | 0x80000000u);
        u64 k = ((u64)m << 10) | (unsigned)j;
        K[t] = k;
        bool lt1 = k < m1;
        u64 nm2 = lt1 ? m1 : ((k < m2) ? k : m2);
        m1 = lt1 ? k : m1;
        m2 = nm2;
    }

    // wave-max(m2) and wave-min(m1)
    u64 tmax = m2, tmin = m1;
#pragma unroll
    for (int off = 1; off < 64; off <<= 1) {
        u64 a = __shfl_xor(tmax, off); if (a > tmax) tmax = a;
        u64 c = __shfl_xor(tmin, off); if (c < tmin) tmin = c;
    }

    // count at T = tmax (guaranteed >= 127); bisect down to <= 192
    u64 T = tmax;
    int chi;
    {
        int c = 0;
#pragma unroll
        for (int t = 0; t < 16; ++t) c += (K[t] < T) ? 1 : 0;
#pragma unroll
        for (int off = 1; off < 64; off <<= 1) c += __shfl_xor(c, off);
        chi = c;
    }
    u64 lo = tmin, hi = T;
    while (chi > 192) {
        u64 mid = (lo + hi) >> 1;
        int c = 0;
#pragma unroll
        for (int t = 0; t < 16; ++t) c += (K[t] < mid) ? 1 : 0;
#pragma unroll
        for (int off = 1; off < 64; off <<= 1) c += __shfl_xor(c, off);
        if (c >= 101) { hi = mid; chi = c; } else lo = mid;
    }
    T = hi;
    const int n = chi;                   // 101 <= n <= 192

    // compact candidates < T via wave prefix-scan
    int myc_n = 0;
#pragma unroll
    for (int t = 0; t < 16; ++t) myc_n += (K[t] < T) ? 1 : 0;
    int sc = myc_n;
#pragma unroll
    for (int off = 1; off < 64; off <<= 1) {
        int v = __shfl_up(sc, off);
        if (lane >= off) sc += v;
    }
    int pos = sc - myc_n;
#pragma unroll
    for (int t = 0; t < 16; ++t) {
        if (K[t] < T) cand[w][pos++] = K[t];
    }
    if (lane == 0) cand[w][n] = ~0ULL;   // sentinel for b128 pair tail
    __syncthreads();

    // exact ranks within compacted set (pairs via b128)
    u64 myc[3]; int rk[3];
#pragma unroll
    for (int q = 0; q < 3; ++q) {
        int i = lane + q * 64;
        myc[q] = (i < n) ? cand[w][i] : ~0ULL;
        rk[q] = 0;
    }
    {
        const ulonglong2* c2 = (const ulonglong2*)&cand[w][0];
        const int half = (n + 1) >> 1;
        for (int jj = 0; jj < half; ++jj) {
            ulonglong2 kk = c2[jj];
#pragma unroll
            for (int q = 0; q < 3; ++q) {
                rk[q] += (kk.x < myc[q]) ? 1 : 0;
                rk[q] += (kk.y < myc[q]) ? 1 : 0;
            }
        }
    }

    // write ranks 1..100 (float4) to global AND LDS (aliasing cand[w] -
    // wave-private region; within-wave LDS ops are ordered)
    const int rowbase = row & ~1023;
    float4* nd4w = (float4*)&cand[w][0];
#pragma unroll
    for (int q = 0; q < 3; ++q) {
        int i = lane + q * 64;
        if (i < n) {
            int r = rk[q];
            if (r >= 1 && r <= 100) {
                int slot = r - 1;
                unsigned j = (unsigned)(myc[q] & 1023u);
                idx_out[row * 100 + slot] = rowbase + (int)j;
                float4 pj = vps[j];
                float dx = pj.x - xi, dy = pj.y - yi, dz = pj.z - zi;
                float nrm = sqrtf(__fadd_rn(__fadd_rn(__fmul_rn(dx, dx),
                                                      __fmul_rn(dy, dy)),
                                            __fmul_rn(dz, dz)));
                float inv = 1.0f / fmaxf(nrm, 1e-12f);
                float4 nv = make_float4(dx * inv, dy * inv, dz * inv, 0.0f);
                nd_out[row * 100 + slot] = nv;
                nd4w[slot] = nv;
            }
        }
    }
    __syncthreads();

    // ---- fused surface conv for the block's 4 rows ----
    const int d = tid & 127;
    float lx = dl[d], ly = dl[128 + d], lz = dl[256 + d];
    float li = 1.0f / fmaxf(sqrtf((lx * lx + ly * ly) + lz * lz), 1e-12f);
    lx *= li; ly *= li; lz *= li;
    float mx = dm[d], my = dm[128 + d], mz = dm[256 + d];
    float mi = 1.0f / fmaxf(sqrtf((mx * mx + my * my) + mz * mz), 1e-12f);
    mx *= mi; my *= mi; mz *= mi;
    float gx = dg[d], gy = dg[128 + d], gz = dg[256 + d];
    float gi = 1.0f / fmaxf(sqrtf((gx * gx + gy * gy) + gz * gz), 1e-12f);
    gx *= gi; gy *= gi; gz *= gi;

#pragma unroll
    for (int p = 0; p < 2; ++p) {
        int rr = (tid >> 7) + 2 * p;     // wave-uniform
        const float4* ns = (const float4*)&cand[rr][0];
        float ml = -1e30f, mm = -1e30f, mg = -1e30f;
        int k = 0;
        for (; k < 5; ++k) {
            float4 v = ns[k];
            ml = fmaxf(ml, (v.x * lx + v.y * ly) + v.z * lz);
            mm = fmaxf(mm, (v.x * mx + v.y * my) + v.z * mz);
            mg = fmaxf(mg, (v.x * gx + v.y * gy) + v.z * gz);
        }
        for (; k < 20; ++k) {
            float4 v = ns[k];
            mm = fmaxf(mm, (v.x * mx + v.y * my) + v.z * mz);
            mg = fmaxf(mg, (v.x * gx + v.y * gy) + v.z * gz);
        }
        for (; k < 100; ++k) {
            float4 v = ns[k];
            mg = fmaxf(mg, (v.x * gx + v.y * gy) + v.z * gz);
        }
        int orow = row0 + rr;
        raw_l[orow * 128 + d] = fmaxf(ml, 0.0f);
        raw_m[orow * 128 + d] = fmaxf(mm, 0.0f);
        raw_g[orow * 128 + d] = fmaxf(mg, 0.0f);
    }
}

// ---------------------------------------------------------------------------
// Kernel 2: BN partial sums: 32 blocks per tensor, 128 rows each, coalesced,
// fp64, deterministic. Layout: p[blk*256+c]=sum, p[blk*256+128+c]=sumsq.
// ---------------------------------------------------------------------------
__global__ __launch_bounds__(256) void bnsum_kernel(
    const float* s0, double* p0,
    const float* s1, double* p1,
    const float* s2, double* p2)
{
    const int t = blockIdx.x >> 5;
    const int blk = blockIdx.x & 31;
    const float* src = (t == 0) ? s0 : (t == 1) ? s1 : s2;
    double* p = (t == 0) ? p0 : (t == 1) ? p1 : p2;
    const int tid = threadIdx.x;
    const int c = tid & 127, seg = tid >> 7;    // 2 segs x 64 rows
    const float* q = src + ((size_t)blk * 128 + seg * 64) * 128 + c;
    double s = 0.0, ss = 0.0;
    for (int r = 0; r < 64; ++r) { float v = q[r * 128]; s += v; ss += (double)v * v; }
    __shared__ double Ls[2][128], Lq[2][128];
    Ls[seg][c] = s; Lq[seg][c] = ss;
    __syncthreads();
    if (tid < 128) {
        p[blk * 256 + c]       = Ls[0][c] + Ls[1][c];
        p[blk * 256 + 128 + c] = Lq[0][c] + Lq[1][c];
    }
}

// st from partials: a = g/sqrt(var+eps), b2 = e - m*a (fp64, deterministic)
__device__ __forceinline__ void compute_st(const double* __restrict__ p,
                                           const float* __restrict__ g,
                                           const float* __restrict__ e,
                                           float* stA, float* stB,
                                           int tid, int nthreads)
{
    for (int c = tid; c < 128; c += nthreads) {
        double S = 0.0, Q = 0.0;
#pragma unroll
        for (int bb = 0; bb < 32; ++bb) { S += p[bb * 256 + c]; Q += p[bb * 256 + 128 + c]; }
        double m = S * (1.0 / 4096.0);
        double var = Q * (1.0 / 4096.0) - m * m;
        double a = (double)g[c] / sqrt(var + 1e-5);
        stA[c] = (float)a;
        stB[c] = (float)((double)e[c] - m * a);
    }
}

// ---------------------------------------------------------------------------
// Kernel 3: dual-job GEMM (CIN=128), 8 rows/block (grid 512 x jobs).
// BN affine derived in-kernel from partials.
// ---------------------------------------------------------------------------
__global__ __launch_bounds__(256) void gemm2_kernel(
    const float* __restrict__ Aa, const double* __restrict__ pa,
    const float* __restrict__ ga, const float* __restrict__ ea,
    const float* __restrict__ Wa, const float* __restrict__ ba, float* __restrict__ outa,
    const float* __restrict__ Ab, const double* __restrict__ pb,
    const float* __restrict__ gb, const float* __restrict__ eb,
    const float* __restrict__ Wb, const float* __restrict__ bb, float* __restrict__ outb)
{
    const int job = blockIdx.y;
    const float* A = job ? Ab : Aa;  const double* p = job ? pb : pa;
    const float* g = job ? gb : ga;  const float* e = job ? eb : ea;
    const float* W = job ? Wb : Wa;  const float* bias = job ? bb : ba;
    float* out = job ? outb : outa;

    __shared__ float stA[128], stB[128];
    __shared__ float As[8 * 128];
    const int o = threadIdx.x;
    const int r0 = blockIdx.x * 8;

    compute_st(p, g, e, stA, stB, o, 256);
    __syncthreads();

    for (int t = o; t < 8 * 128; t += 256) {
        int r = t >> 7, c = t & 127;
        As[t] = fmaxf(fmaf(stA[c], A[(r0 + r) * 128 + c], stB[c]), 0.0f);
    }
    __syncthreads();

    float acc[8];
    const float bz = bias[o];
#pragma unroll
    for (int r = 0; r < 8; ++r) acc[r] = bz;

    for (int c = 0; c < 128; c += 4) {
        float w0 = W[(c + 0) * 256 + o];
        float w1 = W[(c + 1) * 256 + o];
        float w2 = W[(c + 2) * 256 + o];
        float w3 = W[(c + 3) * 256 + o];
#pragma unroll
        for (int r = 0; r < 8; ++r) {
            const float4 av = *(const float4*)&As[r * 128 + c];
            acc[r] += av.x * w0 + av.y * w1 + av.z * w2 + av.w * w3;
        }
    }
#pragma unroll
    for (int r = 0; r < 8; ++r)
        out[(r0 + r) * 256 + o] = acc[r];
}

// ---------------------------------------------------------------------------
// Kernel 4: conv-layer apply, 1 row per 128-thread block, up to 2 jobs via
// blockIdx.y. nd (float4) / idx reads wave-uniform -> scalar loads.
// ---------------------------------------------------------------------------
__global__ __launch_bounds__(128) void layer_kernel(
    const float4* __restrict__ nd, const int* __restrict__ idxbuf,
    const float* dir0, const float* fo0, float* out0, int K0,
    const float* dir1, const float* fo1, float* out1, int K1)
{
    const int job = blockIdx.y;
    const float* dirs = job ? dir1 : dir0;
    const float* fo = job ? fo1 : fo0;
    float* out = job ? out1 : out0;
    const int K = job ? K1 : K0;

    const int d = threadIdx.x;
    const int row = blockIdx.x;

    float dx = dirs[d], dy = dirs[128 + d], dz = dirs[256 + d];
    float di = 1.0f / fmaxf(sqrtf((dx * dx + dy * dy) + dz * dz), 1e-12f);
    dx *= di; dy *= di; dz *= di;

    const float4* ns = nd + (size_t)row * 100;
    const int* ib = idxbuf + (size_t)row * 100;

    float acc = -1e30f;
    for (int k = 0; k < K; ++k) {
        float4 v = ns[k];
        int ix = ib[k];
        float th = fmaxf((v.x * dx + v.y * dy) + v.z * dz, 0.0f);
        float fs = fo[ix * 256 + 128 + d];
        acc = fmaxf(acc, th * fs);
    }
    out[row * 128 + d] = fo[row * 256 + d] + acc;
}

// ---------------------------------------------------------------------------
// Kernel 5: final GEMM (CIN=384), 8 rows/block (grid 512), BN affines for
// 3 segments derived in-kernel, final relu, fp32 out.
// ---------------------------------------------------------------------------
__global__ __launch_bounds__(256) void gemmf_kernel(
    const float* __restrict__ A0, const double* __restrict__ p0,
    const float* __restrict__ g0, const float* __restrict__ e0,
    const float* __restrict__ A1, const double* __restrict__ p1,
    const float* __restrict__ g1, const float* __restrict__ e1,
    const float* __restrict__ A2, const double* __restrict__ p2,
    const float* __restrict__ g2, const float* __restrict__ e2,
    const float* __restrict__ W, const float* __restrict__ bias, float* __restrict__ out)
{
    __shared__ float stA[384], stB[384];
    __shared__ float As[8 * 384];
    const int o = threadIdx.x;
    const int r0 = blockIdx.x * 8;

    compute_st(p0, g0, e0, stA,       stB,       o, 256);
    compute_st(p1, g1, e1, stA + 128, stB + 128, o, 256);
    compute_st(p2, g2, e2, stA + 256, stB + 256, o, 256);
    __syncthreads();

    for (int t = o; t < 8 * 384; t += 256) {
        int r = t / 384, c = t - r * 384;
        int seg = c >> 7, cc = c & 127;
        const float* A = (seg == 0) ? A0 : (seg == 1) ? A1 : A2;
        As[t] = fmaxf(fmaf(stA[c], A[(r0 + r) * 128 + cc], stB[c]), 0.0f);
    }
    __syncthreads();

    float acc[8];
    const float bz = bias[o];
#pragma unroll
    for (int r = 0; r < 8; ++r) acc[r] = bz;

    for (int c = 0; c < 384; c += 4) {
        float w0 = W[(c + 0) * 256 + o];
        float w1 = W[(c + 1) * 256 + o];
        float w2 = W[(c + 2) * 256 + o];
        float w3 = W[(c + 3) * 256 + o];
#pragma unroll
        for (int r = 0; r < 8; ++r) {
            const float4 av = *(const float4*)&As[r * 384 + c];
            acc[r] += av.x * w0 + av.y * w1 + av.z * w2 + av.w * w3;
        }
    }
#pragma unroll
    for (int r = 0; r < 8; ++r)
        out[(r0 + r) * 256 + o] = fmaxf(acc[r], 0.0f);
}

// ---------------------------------------------------------------------------
extern "C" void kernel_launch(void* const* d_in, const int* in_sizes, int n_in,
                              void* d_out, int out_size, void* d_ws, size_t ws_size,
                              hipStream_t stream)
{
    (void)in_sizes; (void)n_in; (void)out_size; (void)ws_size;

    const float* verts   = (const float*)d_in[0];
    const float* dirs_l  = (const float*)d_in[1];
    const float* dirs_m0 = (const float*)d_in[2];
    const float* W_m1    = (const float*)d_in[3];
    const float* b_m1    = (const float*)d_in[4];
    const float* dirs_m1 = (const float*)d_in[5];
    const float* dirs_g0 = (const float*)d_in[6];
    const float* W_g1    = (const float*)d_in[7];
    const float* b_g1    = (const float*)d_in[8];
    const float* dirs_g1 = (const float*)d_in[9];
    const float* W_g2    = (const float*)d_in[10];
    const float* b_g2    = (const float*)d_in[11];
    const float* dirs_g2 = (const float*)d_in[12];
    const float* g_l  = (const float*)d_in[13]; const float* be_l  = (const float*)d_in[14];
    const float* g_m0 = (const float*)d_in[15]; const float* be_m0 = (const float*)d_in[16];
    const float* g_m1 = (const float*)d_in[17]; const float* be_m1 = (const float*)d_in[18];
    const float* g_g0 = (const float*)d_in[19]; const float* be_g0 = (const float*)d_in[20];
    const float* g_g1 = (const float*)d_in[21]; const float* be_g1 = (const float*)d_in[22];
    const float* g_g2 = (const float*)d_in[23]; const float* be_g2 = (const float*)d_in[24];
    const float* W_down = (const float*)d_in[25];
    const float* b_down = (const float*)d_in[26];

    char* ws = (char*)d_ws;
    const size_t MB = 1 << 20;
    int*    idx100 = (int*)   (ws + 0);               // 1.64 MB
    double* p_l    = (double*)(ws + 0x1A0000);        // 6 x 64 KB fp64 partials
    double* p_m0   = p_l  + 8192;
    double* p_m1   = p_m0 + 8192;
    double* p_g0   = p_m1 + 8192;
    double* p_g1   = p_g0 + 8192;
    double* p_g2   = p_g1 + 8192;
    float4* nd100  = (float4*)(ws + 2 * MB);          // 6.55 MB (stride-4)
    float* raw_l  = (float*)(ws +  9 * MB);           // 2 MB each
    float* raw_m0 = (float*)(ws + 11 * MB);
    float* raw_g0 = (float*)(ws + 13 * MB);
    float* raw_m1 = (float*)(ws + 15 * MB);
    float* raw_g1 = (float*)(ws + 17 * MB);
    float* raw_g2 = (float*)(ws + 19 * MB);
    float* fo_m   = (float*)(ws + 21 * MB);           // 4 MB each
    float* fo_g   = (float*)(ws + 25 * MB);
    float* fo_g2  = (float*)(ws + 29 * MB);

    // L1. KNN + nd + fused surface convs (k=5/20/100)
    knnsurf_kernel<<<1024, 256, 0, stream>>>(verts, idx100, nd100,
                                             dirs_l, dirs_m0, dirs_g0,
                                             raw_l, raw_m0, raw_g0);
    // L2. BN partials for l, m0, g0
    bnsum_kernel<<<96, 256, 0, stream>>>(raw_l, p_l, raw_m0, p_m0, raw_g0, p_g0);
    // L3. fo_m = bn_relu(raw_m0) @ W_m1 ; fo_g = bn_relu(raw_g0) @ W_g1
    gemm2_kernel<<<dim3(512, 2), 256, 0, stream>>>(
        raw_m0, p_m0, g_m0, be_m0, W_m1, b_m1, fo_m,
        raw_g0, p_g0, g_g0, be_g0, W_g1, b_g1, fo_g);
    // L4. conv-layer apply (m1: K=20, g1: K=100)
    layer_kernel<<<dim3(4096, 2), 128, 0, stream>>>(nd100, idx100,
                                                    dirs_m1, fo_m, raw_m1, 20,
                                                    dirs_g1, fo_g, raw_g1, 100);
    // L5. BN partials for m1, g1
    bnsum_kernel<<<64, 256, 0, stream>>>(raw_m1, p_m1, raw_g1, p_g1, raw_g1, p_g1);
    // L6. fo_g2 = bn_relu(raw_g1) @ W_g2
    gemm2_kernel<<<dim3(512, 1), 256, 0, stream>>>(
        raw_g1, p_g1, g_g1, be_g1, W_g2, b_g2, fo_g2,
        raw_g1, p_g1, g_g1, be_g1, W_g2, b_g2, fo_g2);
    // L7. conv-layer apply (g2: K=100)
    layer_kernel<<<dim3(4096, 1), 128, 0, stream>>>(nd100, idx100,
                                                    dirs_g2, fo_g2, raw_g2, 100,
                                                    dirs_g2, fo_g2, raw_g2, 100);
    // L8. BN partials for g2
    bnsum_kernel<<<32, 256, 0, stream>>>(raw_g2, p_g2, raw_g2, p_g2, raw_g2, p_g2);
    // L9. final: relu(concat(bn_relu each) @ W_down + b_down) -> fp32 out
    gemmf_kernel<<<512, 256, 0, stream>>>(raw_l, p_l, g_l, be_l,
                                          raw_m1, p_m1, g_m1, be_m1,
                                          raw_g2, p_g2, g_g2, be_g2,
                                          W_down, b_down, (float*)d_out);
}